// Round 1
// baseline (596.998 us; speedup 1.0000x reference)
//
#include <hip/hip_runtime.h>
#include <hip/hip_bf16.h>
#include <math.h>

// Problem constants (from reference)
constexpr int NN  = 50000;          // nodes
constexpr int NE  = 800000;         // edges (before self loops)
constexpr int EP  = NE + NN;        // edges + self loops = 850000
constexpr int FIN = 512;
constexpr int NH  = 8;
constexpr int NC  = 32;
constexpr int HC  = NH * NC;        // 256
constexpr int CLS = 40;

// ---------------------------------------------------------------------------
// CSR build: histogram -> scan -> scatter (sort edges by dst)
// ---------------------------------------------------------------------------
__global__ void k_hist(const int* __restrict__ ei, int* __restrict__ deg) {
  int e = blockIdx.x * 256 + threadIdx.x;
  if (e >= EP) return;
  int d = (e < NE) ? ei[NE + e] : (e - NE);
  atomicAdd(&deg[d], 1);
}

__global__ __launch_bounds__(1024) void k_scan1(const int* __restrict__ deg,
                                                int* __restrict__ rowptr1,
                                                int* __restrict__ bsum, int n) {
  __shared__ int sm[1024];
  int i = blockIdx.x * 1024 + threadIdx.x;
  int v = (i < n) ? deg[i] : 0;
  sm[threadIdx.x] = v;
  __syncthreads();
  for (int off = 1; off < 1024; off <<= 1) {
    int t = (threadIdx.x >= off) ? sm[threadIdx.x - off] : 0;
    __syncthreads();
    sm[threadIdx.x] += t;
    __syncthreads();
  }
  if (i < n) rowptr1[i] = sm[threadIdx.x];
  if (threadIdx.x == 1023) bsum[blockIdx.x] = sm[1023];
}

__global__ void k_scan2(int* __restrict__ bsum, int nb) {
  if (blockIdx.x == 0 && threadIdx.x == 0) {
    int run = 0;
    for (int b = 0; b < nb; ++b) { int t = bsum[b]; bsum[b] = run; run += t; }
  }
}

__global__ void k_scan3(int* __restrict__ rowptr, const int* __restrict__ bsum, int n) {
  int i = blockIdx.x * 256 + threadIdx.x;
  if (i == 0) rowptr[0] = 0;
  if (i < n) rowptr[i + 1] += bsum[i >> 10];
}

__global__ void k_scatter(const int* __restrict__ ei, const int* __restrict__ rowptr,
                          int* __restrict__ cursor, int* __restrict__ srcS,
                          int* __restrict__ pos) {
  int e = blockIdx.x * 256 + threadIdx.x;
  if (e >= EP) return;
  int s, d;
  if (e < NE) { s = ei[e]; d = ei[NE + e]; } else { s = d = e - NE; }
  int p = rowptr[d] + atomicAdd(&cursor[d], 1);
  srcS[p] = s;
  pos[e] = p;
}

// ---------------------------------------------------------------------------
// GEMM1: h1[NN,256] = x[NN,512] @ W1[512,256]   (fp32, LDS-tiled 128x128)
// ---------------------------------------------------------------------------
#define GM_BM 128
#define GM_BN 128
#define GM_BK 16

__global__ __launch_bounds__(256) void k_gemm1(const float* __restrict__ X,
                                               const float* __restrict__ W,
                                               float* __restrict__ Hout) {
  __shared__ __align__(16) float As[GM_BK][GM_BM + 4];
  __shared__ __align__(16) float Bs[GM_BK][GM_BN + 4];
  const int tid = threadIdx.x;
  const int bm = blockIdx.x * GM_BM;
  const int bn = blockIdx.y * GM_BN;
  const int tm = (tid >> 4) * 8;
  const int tn = (tid & 15) * 8;
  const int ra  = tid >> 1;            // 0..127
  const int kca = (tid & 1) * 8;       // 0 or 8
  const int krb = tid >> 4;            // 0..15
  const int ncb = (tid & 15) * 8;      // 0..120
  const int arow = min(bm + ra, NN - 1);

  float acc[8][8];
#pragma unroll
  for (int i = 0; i < 8; ++i)
#pragma unroll
    for (int j = 0; j < 8; ++j) acc[i][j] = 0.f;

  for (int k0 = 0; k0 < FIN; k0 += GM_BK) {
    float4 a0 = *(const float4*)&X[(size_t)arow * FIN + k0 + kca];
    float4 a1 = *(const float4*)&X[(size_t)arow * FIN + k0 + kca + 4];
    float4 b0 = *(const float4*)&W[(size_t)(k0 + krb) * HC + bn + ncb];
    float4 b1 = *(const float4*)&W[(size_t)(k0 + krb) * HC + bn + ncb + 4];
    As[kca + 0][ra] = a0.x; As[kca + 1][ra] = a0.y;
    As[kca + 2][ra] = a0.z; As[kca + 3][ra] = a0.w;
    As[kca + 4][ra] = a1.x; As[kca + 5][ra] = a1.y;
    As[kca + 6][ra] = a1.z; As[kca + 7][ra] = a1.w;
    *(float4*)&Bs[krb][ncb]     = b0;
    *(float4*)&Bs[krb][ncb + 4] = b1;
    __syncthreads();
#pragma unroll
    for (int kk = 0; kk < GM_BK; ++kk) {
      float4 av0 = *(const float4*)&As[kk][tm];
      float4 av1 = *(const float4*)&As[kk][tm + 4];
      float4 bv0 = *(const float4*)&Bs[kk][tn];
      float4 bv1 = *(const float4*)&Bs[kk][tn + 4];
      float a[8] = {av0.x, av0.y, av0.z, av0.w, av1.x, av1.y, av1.z, av1.w};
      float b[8] = {bv0.x, bv0.y, bv0.z, bv0.w, bv1.x, bv1.y, bv1.z, bv1.w};
#pragma unroll
      for (int i = 0; i < 8; ++i)
#pragma unroll
        for (int j = 0; j < 8; ++j) acc[i][j] += a[i] * b[j];
    }
    __syncthreads();
  }
#pragma unroll
  for (int i = 0; i < 8; ++i) {
    int row = bm + tm + i;
    if (row < NN) {
      float4 o0 = {acc[i][0], acc[i][1], acc[i][2], acc[i][3]};
      float4 o1 = {acc[i][4], acc[i][5], acc[i][6], acc[i][7]};
      *(float4*)&Hout[(size_t)row * HC + bn + tn]     = o0;
      *(float4*)&Hout[(size_t)row * HC + bn + tn + 4] = o1;
    }
  }
}

// ---------------------------------------------------------------------------
// alpha1: per (node, head) dot products with a_src1/a_dst1
// ---------------------------------------------------------------------------
__global__ void k_alpha1(const float* __restrict__ h1, const float* __restrict__ a_s,
                         const float* __restrict__ a_d, float* __restrict__ asrc,
                         float* __restrict__ adst) {
  int i = blockIdx.x * 256 + threadIdx.x;
  if (i >= NN * NH) return;
  int n = i >> 3, h = i & 7;
  const float* hp = &h1[(size_t)n * HC + h * NC];
  const float* as = &a_s[h * NC];
  const float* ad = &a_d[h * NC];
  float s = 0.f, d = 0.f;
#pragma unroll
  for (int c = 0; c < NC; ++c) { float v = hp[c]; s += v * as[c]; d += v * ad[c]; }
  asrc[i] = s;
  adst[i] = d;
}

// ---------------------------------------------------------------------------
// edge1: exp(leaky_relu(asrc[src]+adst[dst])) per (edge, head), sorted order
// ---------------------------------------------------------------------------
__global__ void k_edge1(const int* __restrict__ ei, const int* __restrict__ pos,
                        const float* __restrict__ asrc, const float* __restrict__ adst,
                        float* __restrict__ expe) {
  int e = blockIdx.x * 256 + threadIdx.x;
  if (e >= EP) return;
  int s, d;
  if (e < NE) { s = ei[e]; d = ei[NE + e]; } else { s = d = e - NE; }
  int p = pos[e];
#pragma unroll
  for (int h = 0; h < NH; ++h) {
    float v = asrc[s * NH + h] + adst[d * NH + h];
    v = v > 0.f ? v : 0.2f * v;
    expe[(size_t)p * NH + h] = __expf(v);
  }
}

// ---------------------------------------------------------------------------
// agg1: one wave per dst node; lanes cover 256 channels (float4/lane).
// den accumulated per-lane (head = lane>>3). Output: elu(out/den + b1)
// ---------------------------------------------------------------------------
__global__ __launch_bounds__(256) void k_agg1(const float* __restrict__ h1,
                                              const float* __restrict__ expe,
                                              const int* __restrict__ srcS,
                                              const int* __restrict__ rowptr,
                                              const float* __restrict__ b1,
                                              float* __restrict__ helu) {
  int wave = (blockIdx.x * 256 + threadIdx.x) >> 6;
  int lane = threadIdx.x & 63;
  if (wave >= NN) return;
  int lo = rowptr[wave], hi = rowptr[wave + 1];
  int head = lane >> 3;
  float4 acc = {0.f, 0.f, 0.f, 0.f};
  float den = 0.f;
  for (int i = lo; i < hi; ++i) {
    int s = srcS[i];
    float w = expe[(size_t)i * NH + head];
    float4 hv = *(const float4*)&h1[(size_t)s * HC + lane * 4];
    acc.x += w * hv.x; acc.y += w * hv.y; acc.z += w * hv.z; acc.w += w * hv.w;
    den += w;
  }
  float inv = 1.f / (den + 1e-16f);
  float4 bb = *(const float4*)&b1[lane * 4];
  float o[4] = {acc.x * inv + bb.x, acc.y * inv + bb.y,
                acc.z * inv + bb.z, acc.w * inv + bb.w};
#pragma unroll
  for (int j = 0; j < 4; ++j) o[j] = o[j] > 0.f ? o[j] : expm1f(o[j]);
  float4 ov = {o[0], o[1], o[2], o[3]};
  *(float4*)&helu[(size_t)wave * HC + lane * 4] = ov;
}

// ---------------------------------------------------------------------------
// GEMM2: h2[NN,40] = helu[NN,256] @ W2[256,40]
// ---------------------------------------------------------------------------
#define G2_BM 128
#define G2_BK 32

__global__ __launch_bounds__(256) void k_gemm2(const float* __restrict__ A,
                                               const float* __restrict__ W,
                                               float* __restrict__ Hout) {
  __shared__ __align__(16) float As[G2_BK][G2_BM + 4];
  __shared__ float Bs[G2_BK][CLS];
  const int tid = threadIdx.x;
  const int bm = blockIdx.x * G2_BM;
  const int nl = (tid & 31) * 4;       // 4 consecutive nodes
  const int c0 = (tid >> 5) * 5;       // 5 consecutive cols
  const int ra  = tid >> 1;            // 0..127
  const int kca = (tid & 1) * 16;
  const int arow = min(bm + ra, NN - 1);
  float acc[4][5];
#pragma unroll
  for (int i = 0; i < 4; ++i)
#pragma unroll
    for (int j = 0; j < 5; ++j) acc[i][j] = 0.f;

  for (int k0 = 0; k0 < HC; k0 += G2_BK) {
#pragma unroll
    for (int u = 0; u < 4; ++u) {
      float4 av = *(const float4*)&A[(size_t)arow * HC + k0 + kca + u * 4];
      As[kca + u * 4 + 0][ra] = av.x;
      As[kca + u * 4 + 1][ra] = av.y;
      As[kca + u * 4 + 2][ra] = av.z;
      As[kca + u * 4 + 3][ra] = av.w;
    }
    for (int i = tid; i < G2_BK * CLS; i += 256)
      Bs[i / CLS][i % CLS] = W[(size_t)(k0 + i / CLS) * CLS + i % CLS];
    __syncthreads();
#pragma unroll
    for (int kk = 0; kk < G2_BK; ++kk) {
      float4 a = *(const float4*)&As[kk][nl];
      float b0 = Bs[kk][c0 + 0], b1 = Bs[kk][c0 + 1], b2 = Bs[kk][c0 + 2];
      float b3 = Bs[kk][c0 + 3], b4 = Bs[kk][c0 + 4];
      acc[0][0] += a.x * b0; acc[0][1] += a.x * b1; acc[0][2] += a.x * b2; acc[0][3] += a.x * b3; acc[0][4] += a.x * b4;
      acc[1][0] += a.y * b0; acc[1][1] += a.y * b1; acc[1][2] += a.y * b2; acc[1][3] += a.y * b3; acc[1][4] += a.y * b4;
      acc[2][0] += a.z * b0; acc[2][1] += a.z * b1; acc[2][2] += a.z * b2; acc[2][3] += a.z * b3; acc[2][4] += a.z * b4;
      acc[3][0] += a.w * b0; acc[3][1] += a.w * b1; acc[3][2] += a.w * b2; acc[3][3] += a.w * b3; acc[3][4] += a.w * b4;
    }
    __syncthreads();
  }
#pragma unroll
  for (int i = 0; i < 4; ++i) {
    int row = bm + nl + i;
    if (row < NN) {
#pragma unroll
      for (int j = 0; j < 5; ++j) Hout[(size_t)row * CLS + c0 + j] = acc[i][j];
    }
  }
}

// ---------------------------------------------------------------------------
// alpha2: per-node dots with a_src2/a_dst2 (single head)
// ---------------------------------------------------------------------------
__global__ void k_alpha2(const float* __restrict__ h2, const float* __restrict__ a_s,
                         const float* __restrict__ a_d, float* __restrict__ asrc,
                         float* __restrict__ adst) {
  int n = blockIdx.x * 256 + threadIdx.x;
  if (n >= NN) return;
  float s = 0.f, d = 0.f;
#pragma unroll
  for (int c = 0; c < CLS; ++c) {
    float v = h2[(size_t)n * CLS + c];
    s += v * a_s[c];
    d += v * a_d[c];
  }
  asrc[n] = s;
  adst[n] = d;
}

__global__ void k_edge2(const int* __restrict__ ei, const int* __restrict__ pos,
                        const float* __restrict__ asrc, const float* __restrict__ adst,
                        float* __restrict__ expe) {
  int e = blockIdx.x * 256 + threadIdx.x;
  if (e >= EP) return;
  int s, d;
  if (e < NE) { s = ei[e]; d = ei[NE + e]; } else { s = d = e - NE; }
  float v = asrc[s] + adst[d];
  v = v > 0.f ? v : 0.2f * v;
  expe[pos[e]] = __expf(v);
}

// ---------------------------------------------------------------------------
// agg2: one wave per dst node; lanes 0..39 = classes. Fused bias+log_softmax.
// ---------------------------------------------------------------------------
__global__ __launch_bounds__(256) void k_agg2(const float* __restrict__ h2,
                                              const float* __restrict__ expe,
                                              const int* __restrict__ srcS,
                                              const int* __restrict__ rowptr,
                                              const float* __restrict__ b2,
                                              float* __restrict__ out) {
  int wave = (blockIdx.x * 256 + threadIdx.x) >> 6;
  int lane = threadIdx.x & 63;
  if (wave >= NN) return;
  int lo = rowptr[wave], hi = rowptr[wave + 1];
  bool act = lane < CLS;
  float acc = 0.f, den = 0.f;
  for (int i = lo; i < hi; ++i) {
    float w = expe[i];
    den += w;
    int s = srcS[i];
    if (act) acc += w * h2[(size_t)s * CLS + lane];
  }
  float o = act ? (acc / (den + 1e-16f) + b2[lane]) : -INFINITY;
  float m = o;
#pragma unroll
  for (int off = 32; off; off >>= 1) m = fmaxf(m, __shfl_xor(m, off, 64));
  float ex = act ? __expf(o - m) : 0.f;
  float ssum = ex;
#pragma unroll
  for (int off = 32; off; off >>= 1) ssum += __shfl_xor(ssum, off, 64);
  if (act) out[(size_t)wave * CLS + lane] = o - m - logf(ssum);
}

// ---------------------------------------------------------------------------
extern "C" void kernel_launch(void* const* d_in, const int* in_sizes, int n_in,
                              void* d_out, int out_size, void* d_ws, size_t ws_size,
                              hipStream_t stream) {
  const float* x      = (const float*)d_in[0];
  const int*   ei     = (const int*)d_in[1];
  const float* W1     = (const float*)d_in[2];
  const float* a_src1 = (const float*)d_in[3];
  const float* a_dst1 = (const float*)d_in[4];
  const float* b1     = (const float*)d_in[5];
  const float* W2     = (const float*)d_in[6];
  const float* a_src2 = (const float*)d_in[7];
  const float* a_dst2 = (const float*)d_in[8];
  const float* b2     = (const float*)d_in[9];
  float* out = (float*)d_out;

  char* p = (char*)d_ws;
  auto alloc = [&](size_t bytes) {
    char* r = p;
    p += (bytes + 255) & ~size_t(255);
    return r;
  };
  float* h1    = (float*)alloc((size_t)NN * HC * 4);   // 51.2 MB
  float* helu  = (float*)alloc((size_t)NN * HC * 4);   // 51.2 MB
  float* h2    = (float*)alloc((size_t)NN * CLS * 4);  // 8 MB
  float* asrc1 = (float*)alloc((size_t)NN * NH * 4);
  float* adst1 = (float*)alloc((size_t)NN * NH * 4);
  float* asrc2 = (float*)alloc((size_t)NN * 4);
  float* adst2 = (float*)alloc((size_t)NN * 4);
  float* expe1 = (float*)alloc((size_t)EP * NH * 4);   // 27.2 MB
  float* expe2 = (float*)alloc((size_t)EP * 4);
  int*   srcS  = (int*)alloc((size_t)EP * 4);
  int*   pos   = (int*)alloc((size_t)EP * 4);
  int*   deg   = (int*)alloc((size_t)NN * 4);
  int*   cursor= (int*)alloc((size_t)NN * 4);
  int*   rowptr= (int*)alloc((size_t)(NN + 1) * 4);
  int*   bsum  = (int*)alloc(256 * 4);

  hipMemsetAsync(deg, 0, (size_t)NN * 4, stream);
  hipMemsetAsync(cursor, 0, (size_t)NN * 4, stream);

  const int nbScan = (NN + 1023) / 1024;  // 49
  k_hist<<<(EP + 255) / 256, 256, 0, stream>>>(ei, deg);
  k_scan1<<<nbScan, 1024, 0, stream>>>(deg, rowptr + 1, bsum, NN);
  k_scan2<<<1, 64, 0, stream>>>(bsum, nbScan);
  k_scan3<<<(NN + 255) / 256, 256, 0, stream>>>(rowptr, bsum, NN);
  k_scatter<<<(EP + 255) / 256, 256, 0, stream>>>(ei, rowptr, cursor, srcS, pos);

  dim3 g1((NN + GM_BM - 1) / GM_BM, HC / GM_BN);  // 391 x 2
  k_gemm1<<<g1, 256, 0, stream>>>(x, W1, h1);
  k_alpha1<<<(NN * NH + 255) / 256, 256, 0, stream>>>(h1, a_src1, a_dst1, asrc1, adst1);
  k_edge1<<<(EP + 255) / 256, 256, 0, stream>>>(ei, pos, asrc1, adst1, expe1);
  k_agg1<<<(NN + 3) / 4, 256, 0, stream>>>(h1, expe1, srcS, rowptr, b1, helu);

  k_gemm2<<<(NN + G2_BM - 1) / G2_BM, 256, 0, stream>>>(helu, W2, h2);
  k_alpha2<<<(NN + 255) / 256, 256, 0, stream>>>(h2, a_src2, a_dst2, asrc2, adst2);
  k_edge2<<<(EP + 255) / 256, 256, 0, stream>>>(ei, pos, asrc2, adst2, expe2);
  k_agg2<<<(NN + 3) / 4, 256, 0, stream>>>(h2, expe2, srcS, rowptr, b2, out);
}

// Round 2
// 479.171 us; speedup vs baseline: 1.2459x; 1.2459x over previous
//
#include <hip/hip_runtime.h>
#include <hip/hip_bf16.h>
#include <math.h>

// Problem constants (from reference)
constexpr int NN  = 50000;          // nodes
constexpr int NE  = 800000;         // edges (before self loops)
constexpr int EP  = NE + NN;        // edges + self loops = 850000
constexpr int FIN = 512;
constexpr int NH  = 8;
constexpr int NC  = 32;
constexpr int HC  = NH * NC;        // 256
constexpr int CLS = 40;

typedef __attribute__((ext_vector_type(8))) __bf16 bf16x8;
typedef __attribute__((ext_vector_type(4))) float f32x4;

// ---------------------------------------------------------------------------
// CSR build: histogram -> scan -> scatter (sort edges by dst)
// ---------------------------------------------------------------------------
__global__ void k_hist(const int* __restrict__ ei, int* __restrict__ deg) {
  int e = blockIdx.x * 256 + threadIdx.x;
  if (e >= EP) return;
  int d = (e < NE) ? ei[NE + e] : (e - NE);
  atomicAdd(&deg[d], 1);
}

__global__ __launch_bounds__(1024) void k_scan1(const int* __restrict__ deg,
                                                int* __restrict__ rowptr1,
                                                int* __restrict__ bsum, int n) {
  __shared__ int sm[1024];
  int i = blockIdx.x * 1024 + threadIdx.x;
  int v = (i < n) ? deg[i] : 0;
  sm[threadIdx.x] = v;
  __syncthreads();
  for (int off = 1; off < 1024; off <<= 1) {
    int t = (threadIdx.x >= off) ? sm[threadIdx.x - off] : 0;
    __syncthreads();
    sm[threadIdx.x] += t;
    __syncthreads();
  }
  if (i < n) rowptr1[i] = sm[threadIdx.x];
  if (threadIdx.x == 1023) bsum[blockIdx.x] = sm[1023];
}

__global__ void k_scan2(int* __restrict__ bsum, int nb) {
  if (blockIdx.x == 0 && threadIdx.x == 0) {
    int run = 0;
    for (int b = 0; b < nb; ++b) { int t = bsum[b]; bsum[b] = run; run += t; }
  }
}

__global__ void k_scan3(int* __restrict__ rowptr, const int* __restrict__ bsum, int n) {
  int i = blockIdx.x * 256 + threadIdx.x;
  if (i == 0) rowptr[0] = 0;
  if (i < n) rowptr[i + 1] += bsum[i >> 10];
}

__global__ void k_scatter(const int* __restrict__ ei, const int* __restrict__ rowptr,
                          int* __restrict__ cursor, int* __restrict__ srcS,
                          int* __restrict__ pos) {
  int e = blockIdx.x * 256 + threadIdx.x;
  if (e >= EP) return;
  int s, d;
  if (e < NE) { s = ei[e]; d = ei[NE + e]; } else { s = d = e - NE; }
  int p = rowptr[d] + atomicAdd(&cursor[d], 1);
  srcS[p] = s;
  pos[e] = p;
}

// ---------------------------------------------------------------------------
// fp32 -> bf16 conversions
// ---------------------------------------------------------------------------
__global__ __launch_bounds__(256) void k_cvt_x(const float* __restrict__ X,
                                               __bf16* __restrict__ Xb) {
  const size_t total = (size_t)NN * FIN;           // 25.6M, divisible by 8
  size_t stride = (size_t)gridDim.x * 256 * 8;
  for (size_t i = ((size_t)blockIdx.x * 256 + threadIdx.x) * 8; i < total; i += stride) {
    float4 f0 = *(const float4*)&X[i];
    float4 f1 = *(const float4*)&X[i + 4];
    bf16x8 o;
    o[0] = (__bf16)f0.x; o[1] = (__bf16)f0.y; o[2] = (__bf16)f0.z; o[3] = (__bf16)f0.w;
    o[4] = (__bf16)f1.x; o[5] = (__bf16)f1.y; o[6] = (__bf16)f1.z; o[7] = (__bf16)f1.w;
    *(bf16x8*)&Xb[i] = o;
  }
}

// W1 [512][256] fp32 -> Wt [256][512] bf16 (transposed)
__global__ void k_cvt_w1t(const float* __restrict__ W1, __bf16* __restrict__ Wt) {
  int t = blockIdx.x * 256 + threadIdx.x;
  if (t >= HC * (FIN / 8)) return;               // 256 * 64
  int c = t >> 6, kq = (t & 63) * 8;
  bf16x8 o;
#pragma unroll
  for (int j = 0; j < 8; ++j) o[j] = (__bf16)W1[(size_t)(kq + j) * HC + c];
  *(bf16x8*)&Wt[(size_t)c * FIN + kq] = o;
}

// ---------------------------------------------------------------------------
// GEMM1 (bf16 MFMA): h1[NN,256] = Xb[NN,512] @ Wt^T
// 128x128 tile, BK=64, 4 waves (each 64x64 = 4x4 frags of 16x16x32).
// LDS layout per operand: slot(r,kb) = r*8 + (kb ^ (r&7)), 16B per slot
// (XOR swizzle -> minimum 8-way banking on ds_read_b128; staged with
//  global_load_lds width=16 using the inverse-swizzled global source).
// ---------------------------------------------------------------------------
__global__ __launch_bounds__(256) void k_gemm1_mfma(const __bf16* __restrict__ Xb,
                                                    const __bf16* __restrict__ Wt,
                                                    float* __restrict__ Hout) {
  __shared__ __align__(16) __bf16 As[128 * 8 * 8];   // 16 KB
  __shared__ __align__(16) __bf16 Bs[128 * 8 * 8];   // 16 KB
  const int tid  = threadIdx.x;
  const int lane = tid & 63;
  const int w    = tid >> 6;              // wave 0..3
  const int wm   = (w >> 1) * 64;
  const int wn   = (w & 1) * 64;
  const int bm   = blockIdx.x * 128;
  const int bn   = blockIdx.y * 128;

  const int l3 = lane >> 3;               // row-within-inst 0..7
  const int l7 = lane & 7;                // kb slot 0..7
  const int kb_src = l7 ^ l3;             // inverse swizzle on global source

  f32x4 acc[4][4] = {};

  for (int k0 = 0; k0 < FIN; k0 += 64) {
#pragma unroll
    for (int q = 0; q < 4; ++q) {
      const int inst = w * 4 + q;         // 0..15, covers rows inst*8..inst*8+7
      const int r = inst * 8 + l3;
      const int arow = min(bm + r, NN - 1);
      const __bf16* ga = Xb + (size_t)arow * FIN + k0 + kb_src * 8;
      __builtin_amdgcn_global_load_lds(
          (const __attribute__((address_space(1))) void*)ga,
          (__attribute__((address_space(3))) void*)(As + inst * 512), 16, 0, 0);
      const __bf16* gb = Wt + (size_t)(bn + r) * FIN + k0 + kb_src * 8;
      __builtin_amdgcn_global_load_lds(
          (const __attribute__((address_space(1))) void*)gb,
          (__attribute__((address_space(3))) void*)(Bs + inst * 512), 16, 0, 0);
    }
    __syncthreads();

    const int l15 = lane & 15, lg = lane >> 4;
#pragma unroll
    for (int kh = 0; kh < 2; ++kh) {
      const int kb = lg + 4 * kh;
      bf16x8 av[4], bv[4];
#pragma unroll
      for (int mi = 0; mi < 4; ++mi) {
        int r = wm + mi * 16 + l15;
        av[mi] = *(const bf16x8*)(As + (size_t)(r * 8 + (kb ^ (r & 7))) * 8);
      }
#pragma unroll
      for (int ni = 0; ni < 4; ++ni) {
        int c = wn + ni * 16 + l15;
        bv[ni] = *(const bf16x8*)(Bs + (size_t)(c * 8 + (kb ^ (c & 7))) * 8);
      }
#pragma unroll
      for (int mi = 0; mi < 4; ++mi)
#pragma unroll
        for (int ni = 0; ni < 4; ++ni)
          acc[mi][ni] = __builtin_amdgcn_mfma_f32_16x16x32_bf16(
              av[mi], bv[ni], acc[mi][ni], 0, 0, 0);
    }
    __syncthreads();
  }

  // epilogue: C/D layout col = lane&15, row = (lane>>4)*4 + reg
  const int l15 = lane & 15, lg = lane >> 4;
#pragma unroll
  for (int mi = 0; mi < 4; ++mi) {
#pragma unroll
    for (int ni = 0; ni < 4; ++ni) {
      int col = bn + wn + ni * 16 + l15;
#pragma unroll
      for (int r = 0; r < 4; ++r) {
        int row = bm + wm + mi * 16 + lg * 4 + r;
        if (row < NN) Hout[(size_t)row * HC + col] = acc[mi][ni][r];
      }
    }
  }
}

// ---------------------------------------------------------------------------
// alpha1: per (node, head) dot products with a_src1/a_dst1
// ---------------------------------------------------------------------------
__global__ void k_alpha1(const float* __restrict__ h1, const float* __restrict__ a_s,
                         const float* __restrict__ a_d, float* __restrict__ asrc,
                         float* __restrict__ adst) {
  int i = blockIdx.x * 256 + threadIdx.x;
  if (i >= NN * NH) return;
  int n = i >> 3, h = i & 7;
  const float* hp = &h1[(size_t)n * HC + h * NC];
  const float* as = &a_s[h * NC];
  const float* ad = &a_d[h * NC];
  float s = 0.f, d = 0.f;
#pragma unroll
  for (int c = 0; c < NC; ++c) { float v = hp[c]; s += v * as[c]; d += v * ad[c]; }
  asrc[i] = s;
  adst[i] = d;
}

// ---------------------------------------------------------------------------
// edge1: exp(leaky_relu(asrc[src]+adst[dst])) per (edge, head), sorted order
// ---------------------------------------------------------------------------
__global__ void k_edge1(const int* __restrict__ ei, const int* __restrict__ pos,
                        const float* __restrict__ asrc, const float* __restrict__ adst,
                        float* __restrict__ expe) {
  int e = blockIdx.x * 256 + threadIdx.x;
  if (e >= EP) return;
  int s, d;
  if (e < NE) { s = ei[e]; d = ei[NE + e]; } else { s = d = e - NE; }
  int p = pos[e];
#pragma unroll
  for (int h = 0; h < NH; ++h) {
    float v = asrc[s * NH + h] + adst[d * NH + h];
    v = v > 0.f ? v : 0.2f * v;
    expe[(size_t)p * NH + h] = __expf(v);
  }
}

// ---------------------------------------------------------------------------
// agg1: one wave per dst node; lanes cover 256 channels (float4/lane).
// ---------------------------------------------------------------------------
__global__ __launch_bounds__(256) void k_agg1(const float* __restrict__ h1,
                                              const float* __restrict__ expe,
                                              const int* __restrict__ srcS,
                                              const int* __restrict__ rowptr,
                                              const float* __restrict__ b1,
                                              float* __restrict__ helu) {
  int wave = (blockIdx.x * 256 + threadIdx.x) >> 6;
  int lane = threadIdx.x & 63;
  if (wave >= NN) return;
  int lo = rowptr[wave], hi = rowptr[wave + 1];
  int head = lane >> 3;
  float4 acc = {0.f, 0.f, 0.f, 0.f};
  float den = 0.f;
  for (int i = lo; i < hi; ++i) {
    int s = srcS[i];
    float w = expe[(size_t)i * NH + head];
    float4 hv = *(const float4*)&h1[(size_t)s * HC + lane * 4];
    acc.x += w * hv.x; acc.y += w * hv.y; acc.z += w * hv.z; acc.w += w * hv.w;
    den += w;
  }
  float inv = 1.f / (den + 1e-16f);
  float4 bb = *(const float4*)&b1[lane * 4];
  float o[4] = {acc.x * inv + bb.x, acc.y * inv + bb.y,
                acc.z * inv + bb.z, acc.w * inv + bb.w};
#pragma unroll
  for (int j = 0; j < 4; ++j) o[j] = o[j] > 0.f ? o[j] : expm1f(o[j]);
  float4 ov = {o[0], o[1], o[2], o[3]};
  *(float4*)&helu[(size_t)wave * HC + lane * 4] = ov;
}

// ---------------------------------------------------------------------------
// GEMM2: h2[NN,40] = helu[NN,256] @ W2[256,40]   (fp32 tiled)
// ---------------------------------------------------------------------------
#define G2_BM 128
#define G2_BK 32

__global__ __launch_bounds__(256) void k_gemm2(const float* __restrict__ A,
                                               const float* __restrict__ W,
                                               float* __restrict__ Hout) {
  __shared__ __align__(16) float As[G2_BK][G2_BM + 4];
  __shared__ float Bs[G2_BK][CLS];
  const int tid = threadIdx.x;
  const int bm = blockIdx.x * G2_BM;
  const int nl = (tid & 31) * 4;
  const int c0 = (tid >> 5) * 5;
  const int ra  = tid >> 1;
  const int kca = (tid & 1) * 16;
  const int arow = min(bm + ra, NN - 1);
  float acc[4][5];
#pragma unroll
  for (int i = 0; i < 4; ++i)
#pragma unroll
    for (int j = 0; j < 5; ++j) acc[i][j] = 0.f;

  for (int k0 = 0; k0 < HC; k0 += G2_BK) {
#pragma unroll
    for (int u = 0; u < 4; ++u) {
      float4 av = *(const float4*)&A[(size_t)arow * HC + k0 + kca + u * 4];
      As[kca + u * 4 + 0][ra] = av.x;
      As[kca + u * 4 + 1][ra] = av.y;
      As[kca + u * 4 + 2][ra] = av.z;
      As[kca + u * 4 + 3][ra] = av.w;
    }
    for (int i = tid; i < G2_BK * CLS; i += 256)
      Bs[i / CLS][i % CLS] = W[(size_t)(k0 + i / CLS) * CLS + i % CLS];
    __syncthreads();
#pragma unroll
    for (int kk = 0; kk < G2_BK; ++kk) {
      float4 a = *(const float4*)&As[kk][nl];
      float b0 = Bs[kk][c0 + 0], b1 = Bs[kk][c0 + 1], b2 = Bs[kk][c0 + 2];
      float b3 = Bs[kk][c0 + 3], b4 = Bs[kk][c0 + 4];
      acc[0][0] += a.x * b0; acc[0][1] += a.x * b1; acc[0][2] += a.x * b2; acc[0][3] += a.x * b3; acc[0][4] += a.x * b4;
      acc[1][0] += a.y * b0; acc[1][1] += a.y * b1; acc[1][2] += a.y * b2; acc[1][3] += a.y * b3; acc[1][4] += a.y * b4;
      acc[2][0] += a.z * b0; acc[2][1] += a.z * b1; acc[2][2] += a.z * b2; acc[2][3] += a.z * b3; acc[2][4] += a.z * b4;
      acc[3][0] += a.w * b0; acc[3][1] += a.w * b1; acc[3][2] += a.w * b2; acc[3][3] += a.w * b3; acc[3][4] += a.w * b4;
    }
    __syncthreads();
  }
#pragma unroll
  for (int i = 0; i < 4; ++i) {
    int row = bm + nl + i;
    if (row < NN) {
#pragma unroll
      for (int j = 0; j < 5; ++j) Hout[(size_t)row * CLS + c0 + j] = acc[i][j];
    }
  }
}

// ---------------------------------------------------------------------------
// alpha2 / edge2 / agg2 (single head, fused bias+log_softmax)
// ---------------------------------------------------------------------------
__global__ void k_alpha2(const float* __restrict__ h2, const float* __restrict__ a_s,
                         const float* __restrict__ a_d, float* __restrict__ asrc,
                         float* __restrict__ adst) {
  int n = blockIdx.x * 256 + threadIdx.x;
  if (n >= NN) return;
  float s = 0.f, d = 0.f;
#pragma unroll
  for (int c = 0; c < CLS; ++c) {
    float v = h2[(size_t)n * CLS + c];
    s += v * a_s[c];
    d += v * a_d[c];
  }
  asrc[n] = s;
  adst[n] = d;
}

__global__ void k_edge2(const int* __restrict__ ei, const int* __restrict__ pos,
                        const float* __restrict__ asrc, const float* __restrict__ adst,
                        float* __restrict__ expe) {
  int e = blockIdx.x * 256 + threadIdx.x;
  if (e >= EP) return;
  int s, d;
  if (e < NE) { s = ei[e]; d = ei[NE + e]; } else { s = d = e - NE; }
  float v = asrc[s] + adst[d];
  v = v > 0.f ? v : 0.2f * v;
  expe[pos[e]] = __expf(v);
}

__global__ __launch_bounds__(256) void k_agg2(const float* __restrict__ h2,
                                              const float* __restrict__ expe,
                                              const int* __restrict__ srcS,
                                              const int* __restrict__ rowptr,
                                              const float* __restrict__ b2,
                                              float* __restrict__ out) {
  int wave = (blockIdx.x * 256 + threadIdx.x) >> 6;
  int lane = threadIdx.x & 63;
  if (wave >= NN) return;
  int lo = rowptr[wave], hi = rowptr[wave + 1];
  bool act = lane < CLS;
  float acc = 0.f, den = 0.f;
  for (int i = lo; i < hi; ++i) {
    float w = expe[i];
    den += w;
    int s = srcS[i];
    if (act) acc += w * h2[(size_t)s * CLS + lane];
  }
  float o = act ? (acc / (den + 1e-16f) + b2[lane]) : -INFINITY;
  float m = o;
#pragma unroll
  for (int off = 32; off; off >>= 1) m = fmaxf(m, __shfl_xor(m, off, 64));
  float ex = act ? __expf(o - m) : 0.f;
  float ssum = ex;
#pragma unroll
  for (int off = 32; off; off >>= 1) ssum += __shfl_xor(ssum, off, 64);
  if (act) out[(size_t)wave * CLS + lane] = o - m - logf(ssum);
}

// ---------------------------------------------------------------------------
extern "C" void kernel_launch(void* const* d_in, const int* in_sizes, int n_in,
                              void* d_out, int out_size, void* d_ws, size_t ws_size,
                              hipStream_t stream) {
  const float* x      = (const float*)d_in[0];
  const int*   ei     = (const int*)d_in[1];
  const float* W1     = (const float*)d_in[2];
  const float* a_src1 = (const float*)d_in[3];
  const float* a_dst1 = (const float*)d_in[4];
  const float* b1     = (const float*)d_in[5];
  const float* W2     = (const float*)d_in[6];
  const float* a_src2 = (const float*)d_in[7];
  const float* a_dst2 = (const float*)d_in[8];
  const float* b2     = (const float*)d_in[9];
  float* out = (float*)d_out;

  char* p = (char*)d_ws;
  auto alloc = [&](size_t bytes) {
    char* r = p;
    p += (bytes + 255) & ~size_t(255);
    return r;
  };
  float*  h1    = (float*)alloc((size_t)NN * HC * 4);    // 51.2 MB
  __bf16* Xb    = (__bf16*)alloc((size_t)NN * FIN * 2);  // 51.2 MB (aliased by helu later)
  float*  helu  = (float*)Xb;                            // Xb dead after gemm1
  __bf16* Wt    = (__bf16*)alloc((size_t)HC * FIN * 2);  // 256 KB
  float*  h2    = (float*)alloc((size_t)NN * CLS * 4);   // 8 MB
  float*  asrc1 = (float*)alloc((size_t)NN * NH * 4);
  float*  adst1 = (float*)alloc((size_t)NN * NH * 4);
  float*  asrc2 = (float*)alloc((size_t)NN * 4);
  float*  adst2 = (float*)alloc((size_t)NN * 4);
  float*  expe1 = (float*)alloc((size_t)EP * NH * 4);    // 27.2 MB
  float*  expe2 = (float*)alloc((size_t)EP * 4);
  int*    srcS  = (int*)alloc((size_t)EP * 4);
  int*    pos   = (int*)alloc((size_t)EP * 4);
  int*    deg   = (int*)alloc((size_t)NN * 4);
  int*    cursor= (int*)alloc((size_t)NN * 4);
  int*    rowptr= (int*)alloc((size_t)(NN + 1) * 4);
  int*    bsum  = (int*)alloc(256 * 4);

  hipMemsetAsync(deg, 0, (size_t)NN * 4, stream);
  hipMemsetAsync(cursor, 0, (size_t)NN * 4, stream);

  const int nbScan = (NN + 1023) / 1024;  // 49
  k_hist<<<(EP + 255) / 256, 256, 0, stream>>>(ei, deg);
  k_scan1<<<nbScan, 1024, 0, stream>>>(deg, rowptr + 1, bsum, NN);
  k_scan2<<<1, 64, 0, stream>>>(bsum, nbScan);
  k_scan3<<<(NN + 255) / 256, 256, 0, stream>>>(rowptr, bsum, NN);
  k_scatter<<<(EP + 255) / 256, 256, 0, stream>>>(ei, rowptr, cursor, srcS, pos);

  k_cvt_x<<<2048, 256, 0, stream>>>(x, Xb);
  k_cvt_w1t<<<(HC * (FIN / 8) + 255) / 256, 256, 0, stream>>>(W1, Wt);

  dim3 g1((NN + 127) / 128, HC / 128);  // 391 x 2
  k_gemm1_mfma<<<g1, 256, 0, stream>>>(Xb, Wt, h1);
  k_alpha1<<<(NN * NH + 255) / 256, 256, 0, stream>>>(h1, a_src1, a_dst1, asrc1, adst1);
  k_edge1<<<(EP + 255) / 256, 256, 0, stream>>>(ei, pos, asrc1, adst1, expe1);
  k_agg1<<<(NN + 3) / 4, 256, 0, stream>>>(h1, expe1, srcS, rowptr, b1, helu);

  k_gemm2<<<(NN + G2_BM - 1) / G2_BM, 256, 0, stream>>>(helu, W2, h2);
  k_alpha2<<<(NN + 255) / 256, 256, 0, stream>>>(h2, a_src2, a_dst2, asrc2, adst2);
  k_edge2<<<(EP + 255) / 256, 256, 0, stream>>>(ei, pos, asrc2, adst2, expe2);
  k_agg2<<<(NN + 3) / 4, 256, 0, stream>>>(h2, expe2, srcS, rowptr, b2, out);
}

// Round 3
// 402.419 us; speedup vs baseline: 1.4835x; 1.1907x over previous
//
#include <hip/hip_runtime.h>
#include <hip/hip_bf16.h>
#include <math.h>

// Problem constants (from reference)
constexpr int NN  = 50000;          // nodes
constexpr int NE  = 800000;         // edges (before self loops)
constexpr int EP  = NE + NN;        // edges + self loops = 850000
constexpr int FIN = 512;
constexpr int NH  = 8;
constexpr int NC  = 32;
constexpr int HC  = NH * NC;        // 256
constexpr int CLS = 40;

typedef __attribute__((ext_vector_type(8))) __bf16 bf16x8;
typedef __attribute__((ext_vector_type(4))) __bf16 bf16x4;
typedef __attribute__((ext_vector_type(4))) float f32x4;

// ---------------------------------------------------------------------------
// CSR build: histogram -> scan -> scatter (sort edges by dst)
// ---------------------------------------------------------------------------
__global__ void k_hist(const int* __restrict__ ei, int* __restrict__ deg) {
  int e = blockIdx.x * 256 + threadIdx.x;
  if (e >= EP) return;
  int d = (e < NE) ? ei[NE + e] : (e - NE);
  atomicAdd(&deg[d], 1);
}

__global__ __launch_bounds__(1024) void k_scan1(const int* __restrict__ deg,
                                                int* __restrict__ rowptr1,
                                                int* __restrict__ bsum, int n) {
  __shared__ int sm[1024];
  int i = blockIdx.x * 1024 + threadIdx.x;
  int v = (i < n) ? deg[i] : 0;
  sm[threadIdx.x] = v;
  __syncthreads();
  for (int off = 1; off < 1024; off <<= 1) {
    int t = (threadIdx.x >= off) ? sm[threadIdx.x - off] : 0;
    __syncthreads();
    sm[threadIdx.x] += t;
    __syncthreads();
  }
  if (i < n) rowptr1[i] = sm[threadIdx.x];
  if (threadIdx.x == 1023) bsum[blockIdx.x] = sm[1023];
}

__global__ void k_scan2(int* __restrict__ bsum, int nb) {
  if (blockIdx.x == 0 && threadIdx.x == 0) {
    int run = 0;
    for (int b = 0; b < nb; ++b) { int t = bsum[b]; bsum[b] = run; run += t; }
  }
}

__global__ void k_scan3(int* __restrict__ rowptr, const int* __restrict__ bsum, int n) {
  int i = blockIdx.x * 256 + threadIdx.x;
  if (i == 0) rowptr[0] = 0;
  if (i < n) rowptr[i + 1] += bsum[i >> 10];
}

__global__ void k_scatter(const int* __restrict__ ei, const int* __restrict__ rowptr,
                          int* __restrict__ cursor, int* __restrict__ srcS) {
  int e = blockIdx.x * 256 + threadIdx.x;
  if (e >= EP) return;
  int s, d;
  if (e < NE) { s = ei[e]; d = ei[NE + e]; } else { s = d = e - NE; }
  int p = rowptr[d] + atomicAdd(&cursor[d], 1);
  srcS[p] = s;
}

// ---------------------------------------------------------------------------
// fp32 -> bf16 conversions
// ---------------------------------------------------------------------------
__global__ __launch_bounds__(256) void k_cvt_x(const float* __restrict__ X,
                                               __bf16* __restrict__ Xb) {
  const size_t total = (size_t)NN * FIN;           // 25.6M, divisible by 8
  size_t stride = (size_t)gridDim.x * 256 * 8;
  for (size_t i = ((size_t)blockIdx.x * 256 + threadIdx.x) * 8; i < total; i += stride) {
    float4 f0 = *(const float4*)&X[i];
    float4 f1 = *(const float4*)&X[i + 4];
    bf16x8 o;
    o[0] = (__bf16)f0.x; o[1] = (__bf16)f0.y; o[2] = (__bf16)f0.z; o[3] = (__bf16)f0.w;
    o[4] = (__bf16)f1.x; o[5] = (__bf16)f1.y; o[6] = (__bf16)f1.z; o[7] = (__bf16)f1.w;
    *(bf16x8*)&Xb[i] = o;
  }
}

// W1 [512][256] fp32 -> Wt [256][512] bf16 (transposed)
__global__ void k_cvt_w1t(const float* __restrict__ W1, __bf16* __restrict__ Wt) {
  int t = blockIdx.x * 256 + threadIdx.x;
  if (t >= HC * (FIN / 8)) return;               // 256 * 64
  int c = t >> 6, kq = (t & 63) * 8;
  bf16x8 o;
#pragma unroll
  for (int j = 0; j < 8; ++j) o[j] = (__bf16)W1[(size_t)(kq + j) * HC + c];
  *(bf16x8*)&Wt[(size_t)c * FIN + kq] = o;
}

// ---------------------------------------------------------------------------
// GEMM1 (bf16 MFMA): h1b[NN,256](bf16) = Xb[NN,512] @ Wt^T
// 128x128 tile, BK=64, 4 waves. XOR-swizzled LDS + global_load_lds w=16.
// ---------------------------------------------------------------------------
__global__ __launch_bounds__(256) void k_gemm1_mfma(const __bf16* __restrict__ Xb,
                                                    const __bf16* __restrict__ Wt,
                                                    __bf16* __restrict__ Hout) {
  __shared__ __align__(16) __bf16 As[128 * 8 * 8];   // 16 KB
  __shared__ __align__(16) __bf16 Bs[128 * 8 * 8];   // 16 KB
  const int tid  = threadIdx.x;
  const int lane = tid & 63;
  const int w    = tid >> 6;              // wave 0..3
  const int wm   = (w >> 1) * 64;
  const int wn   = (w & 1) * 64;
  const int bm   = blockIdx.x * 128;
  const int bn   = blockIdx.y * 128;

  const int l3 = lane >> 3;               // row-within-inst 0..7
  const int l7 = lane & 7;                // kb slot 0..7
  const int kb_src = l7 ^ l3;             // inverse swizzle on global source

  f32x4 acc[4][4] = {};

  for (int k0 = 0; k0 < FIN; k0 += 64) {
#pragma unroll
    for (int q = 0; q < 4; ++q) {
      const int inst = w * 4 + q;         // 0..15, covers rows inst*8..inst*8+7
      const int r = inst * 8 + l3;
      const int arow = min(bm + r, NN - 1);
      const __bf16* ga = Xb + (size_t)arow * FIN + k0 + kb_src * 8;
      __builtin_amdgcn_global_load_lds(
          (const __attribute__((address_space(1))) void*)ga,
          (__attribute__((address_space(3))) void*)(As + inst * 512), 16, 0, 0);
      const __bf16* gb = Wt + (size_t)(bn + r) * FIN + k0 + kb_src * 8;
      __builtin_amdgcn_global_load_lds(
          (const __attribute__((address_space(1))) void*)gb,
          (__attribute__((address_space(3))) void*)(Bs + inst * 512), 16, 0, 0);
    }
    __syncthreads();

    const int l15 = lane & 15, lg = lane >> 4;
#pragma unroll
    for (int kh = 0; kh < 2; ++kh) {
      const int kb = lg + 4 * kh;
      bf16x8 av[4], bv[4];
#pragma unroll
      for (int mi = 0; mi < 4; ++mi) {
        int r = wm + mi * 16 + l15;
        av[mi] = *(const bf16x8*)(As + (size_t)(r * 8 + (kb ^ (r & 7))) * 8);
      }
#pragma unroll
      for (int ni = 0; ni < 4; ++ni) {
        int c = wn + ni * 16 + l15;
        bv[ni] = *(const bf16x8*)(Bs + (size_t)(c * 8 + (kb ^ (c & 7))) * 8);
      }
#pragma unroll
      for (int mi = 0; mi < 4; ++mi)
#pragma unroll
        for (int ni = 0; ni < 4; ++ni)
          acc[mi][ni] = __builtin_amdgcn_mfma_f32_16x16x32_bf16(
              av[mi], bv[ni], acc[mi][ni], 0, 0, 0);
    }
    __syncthreads();
  }

  // epilogue: C/D layout col = lane&15, row = (lane>>4)*4 + reg; store bf16
  const int l15 = lane & 15, lg = lane >> 4;
#pragma unroll
  for (int mi = 0; mi < 4; ++mi) {
#pragma unroll
    for (int ni = 0; ni < 4; ++ni) {
      int col = bn + wn + ni * 16 + l15;
#pragma unroll
      for (int r = 0; r < 4; ++r) {
        int row = bm + wm + mi * 16 + lg * 4 + r;
        if (row < NN) Hout[(size_t)row * HC + col] = (__bf16)acc[mi][ni][r];
      }
    }
  }
}

// ---------------------------------------------------------------------------
// alpha1: per (node, head) dot products with a_src1/a_dst1 (bf16 h1)
// ---------------------------------------------------------------------------
__global__ void k_alpha1(const __bf16* __restrict__ h1b, const float* __restrict__ a_s,
                         const float* __restrict__ a_d, float* __restrict__ asrc,
                         float* __restrict__ adst) {
  int i = blockIdx.x * 256 + threadIdx.x;
  if (i >= NN * NH) return;
  int n = i >> 3, h = i & 7;
  const __bf16* hp = &h1b[(size_t)n * HC + h * NC];
  const float* as = &a_s[h * NC];
  const float* ad = &a_d[h * NC];
  float s = 0.f, d = 0.f;
#pragma unroll
  for (int q = 0; q < 4; ++q) {
    bf16x8 v = *(const bf16x8*)&hp[q * 8];
#pragma unroll
    for (int j = 0; j < 8; ++j) {
      float f = (float)v[j];
      s += f * as[q * 8 + j];
      d += f * ad[q * 8 + j];
    }
  }
  asrc[i] = s;
  adst[i] = d;
}

// ---------------------------------------------------------------------------
// agg1: one wave per dst node; lanes cover 256 channels (bf16x4 = 8B/lane).
// Edge weight computed inline: w = exp(leakyrelu(asrc[s]+adst[dst])).
// Output: elu(acc/den + b1), fp32.
// ---------------------------------------------------------------------------
__global__ __launch_bounds__(256) void k_agg1(const __bf16* __restrict__ h1b,
                                              const float* __restrict__ asrc,
                                              const float* __restrict__ adst,
                                              const int* __restrict__ srcS,
                                              const int* __restrict__ rowptr,
                                              const float* __restrict__ b1,
                                              float* __restrict__ helu) {
  int wave = (blockIdx.x * 256 + threadIdx.x) >> 6;
  int lane = threadIdx.x & 63;
  if (wave >= NN) return;
  int lo = rowptr[wave], hi = rowptr[wave + 1];
  int head = lane >> 3;
  float adstv = adst[wave * NH + head];
  float4 acc = {0.f, 0.f, 0.f, 0.f};
  float den = 0.f;
  for (int i = lo; i < hi; ++i) {
    int s = srcS[i];
    float v = asrc[s * NH + head] + adstv;
    v = v > 0.f ? v : 0.2f * v;
    float w = __expf(v);
    bf16x4 hv = *(const bf16x4*)&h1b[(size_t)s * HC + lane * 4];
    acc.x += w * (float)hv[0];
    acc.y += w * (float)hv[1];
    acc.z += w * (float)hv[2];
    acc.w += w * (float)hv[3];
    den += w;
  }
  float inv = 1.f / (den + 1e-16f);
  float4 bb = *(const float4*)&b1[lane * 4];
  float o[4] = {acc.x * inv + bb.x, acc.y * inv + bb.y,
                acc.z * inv + bb.z, acc.w * inv + bb.w};
#pragma unroll
  for (int j = 0; j < 4; ++j) o[j] = o[j] > 0.f ? o[j] : expm1f(o[j]);
  float4 ov = {o[0], o[1], o[2], o[3]};
  *(float4*)&helu[(size_t)wave * HC + lane * 4] = ov;
}

// ---------------------------------------------------------------------------
// GEMM2: h2b[NN,40](bf16) = helu[NN,256] @ W2[256,40]   (fp32 tiled)
// ---------------------------------------------------------------------------
#define G2_BM 128
#define G2_BK 32

__global__ __launch_bounds__(256) void k_gemm2(const float* __restrict__ A,
                                               const float* __restrict__ W,
                                               __bf16* __restrict__ Hout) {
  __shared__ __align__(16) float As[G2_BK][G2_BM + 4];
  __shared__ float Bs[G2_BK][CLS];
  const int tid = threadIdx.x;
  const int bm = blockIdx.x * G2_BM;
  const int nl = (tid & 31) * 4;
  const int c0 = (tid >> 5) * 5;
  const int ra  = tid >> 1;
  const int kca = (tid & 1) * 16;
  const int arow = min(bm + ra, NN - 1);
  float acc[4][5];
#pragma unroll
  for (int i = 0; i < 4; ++i)
#pragma unroll
    for (int j = 0; j < 5; ++j) acc[i][j] = 0.f;

  for (int k0 = 0; k0 < HC; k0 += G2_BK) {
#pragma unroll
    for (int u = 0; u < 4; ++u) {
      float4 av = *(const float4*)&A[(size_t)arow * HC + k0 + kca + u * 4];
      As[kca + u * 4 + 0][ra] = av.x;
      As[kca + u * 4 + 1][ra] = av.y;
      As[kca + u * 4 + 2][ra] = av.z;
      As[kca + u * 4 + 3][ra] = av.w;
    }
    for (int i = tid; i < G2_BK * CLS; i += 256)
      Bs[i / CLS][i % CLS] = W[(size_t)(k0 + i / CLS) * CLS + i % CLS];
    __syncthreads();
#pragma unroll
    for (int kk = 0; kk < G2_BK; ++kk) {
      float4 a = *(const float4*)&As[kk][nl];
      float b0 = Bs[kk][c0 + 0], b1 = Bs[kk][c0 + 1], b2 = Bs[kk][c0 + 2];
      float b3 = Bs[kk][c0 + 3], b4 = Bs[kk][c0 + 4];
      acc[0][0] += a.x * b0; acc[0][1] += a.x * b1; acc[0][2] += a.x * b2; acc[0][3] += a.x * b3; acc[0][4] += a.x * b4;
      acc[1][0] += a.y * b0; acc[1][1] += a.y * b1; acc[1][2] += a.y * b2; acc[1][3] += a.y * b3; acc[1][4] += a.y * b4;
      acc[2][0] += a.z * b0; acc[2][1] += a.z * b1; acc[2][2] += a.z * b2; acc[2][3] += a.z * b3; acc[2][4] += a.z * b4;
      acc[3][0] += a.w * b0; acc[3][1] += a.w * b1; acc[3][2] += a.w * b2; acc[3][3] += a.w * b3; acc[3][4] += a.w * b4;
    }
    __syncthreads();
  }
#pragma unroll
  for (int i = 0; i < 4; ++i) {
    int row = bm + nl + i;
    if (row < NN) {
#pragma unroll
      for (int j = 0; j < 5; ++j) Hout[(size_t)row * CLS + c0 + j] = (__bf16)acc[i][j];
    }
  }
}

// ---------------------------------------------------------------------------
// alpha2: per-node dots with a_src2/a_dst2 (single head, bf16 h2)
// ---------------------------------------------------------------------------
__global__ void k_alpha2(const __bf16* __restrict__ h2b, const float* __restrict__ a_s,
                         const float* __restrict__ a_d, float* __restrict__ asrc,
                         float* __restrict__ adst) {
  int n = blockIdx.x * 256 + threadIdx.x;
  if (n >= NN) return;
  float s = 0.f, d = 0.f;
#pragma unroll
  for (int q = 0; q < 5; ++q) {
    bf16x8 v = *(const bf16x8*)&h2b[(size_t)n * CLS + q * 8];
#pragma unroll
    for (int j = 0; j < 8; ++j) {
      float f = (float)v[j];
      s += f * a_s[q * 8 + j];
      d += f * a_d[q * 8 + j];
    }
  }
  asrc[n] = s;
  adst[n] = d;
}

// ---------------------------------------------------------------------------
// agg2: one wave per dst node; lanes 0..39 = classes; inline edge weights;
// fused bias + log_softmax.
// ---------------------------------------------------------------------------
__global__ __launch_bounds__(256) void k_agg2(const __bf16* __restrict__ h2b,
                                              const float* __restrict__ asrc,
                                              const float* __restrict__ adst,
                                              const int* __restrict__ srcS,
                                              const int* __restrict__ rowptr,
                                              const float* __restrict__ b2,
                                              float* __restrict__ out) {
  int wave = (blockIdx.x * 256 + threadIdx.x) >> 6;
  int lane = threadIdx.x & 63;
  if (wave >= NN) return;
  int lo = rowptr[wave], hi = rowptr[wave + 1];
  bool act = lane < CLS;
  float adstv = adst[wave];
  float acc = 0.f, den = 0.f;
  for (int i = lo; i < hi; ++i) {
    int s = srcS[i];
    float v = asrc[s] + adstv;
    v = v > 0.f ? v : 0.2f * v;
    float w = __expf(v);
    den += w;
    if (act) acc += w * (float)h2b[(size_t)s * CLS + lane];
  }
  float o = act ? (acc / (den + 1e-16f) + b2[lane]) : -INFINITY;
  float m = o;
#pragma unroll
  for (int off = 32; off; off >>= 1) m = fmaxf(m, __shfl_xor(m, off, 64));
  float ex = act ? __expf(o - m) : 0.f;
  float ssum = ex;
#pragma unroll
  for (int off = 32; off; off >>= 1) ssum += __shfl_xor(ssum, off, 64);
  if (act) out[(size_t)wave * CLS + lane] = o - m - logf(ssum);
}

// ---------------------------------------------------------------------------
extern "C" void kernel_launch(void* const* d_in, const int* in_sizes, int n_in,
                              void* d_out, int out_size, void* d_ws, size_t ws_size,
                              hipStream_t stream) {
  const float* x      = (const float*)d_in[0];
  const int*   ei     = (const int*)d_in[1];
  const float* W1     = (const float*)d_in[2];
  const float* a_src1 = (const float*)d_in[3];
  const float* a_dst1 = (const float*)d_in[4];
  const float* b1     = (const float*)d_in[5];
  const float* W2     = (const float*)d_in[6];
  const float* a_src2 = (const float*)d_in[7];
  const float* a_dst2 = (const float*)d_in[8];
  const float* b2     = (const float*)d_in[9];
  float* out = (float*)d_out;

  char* p = (char*)d_ws;
  auto alloc = [&](size_t bytes) {
    char* r = p;
    p += (bytes + 255) & ~size_t(255);
    return r;
  };
  __bf16* h1b   = (__bf16*)alloc((size_t)NN * HC * 2);   // 25.6 MB
  __bf16* Xb    = (__bf16*)alloc((size_t)NN * FIN * 2);  // 51.2 MB (aliased by helu)
  float*  helu  = (float*)Xb;                            // Xb dead after gemm1
  __bf16* Wt    = (__bf16*)alloc((size_t)HC * FIN * 2);  // 256 KB
  __bf16* h2b   = (__bf16*)alloc((size_t)NN * CLS * 2);  // 4 MB
  float*  asrc1 = (float*)alloc((size_t)NN * NH * 4);
  float*  adst1 = (float*)alloc((size_t)NN * NH * 4);
  float*  asrc2 = (float*)alloc((size_t)NN * 4);
  float*  adst2 = (float*)alloc((size_t)NN * 4);
  int*    srcS  = (int*)alloc((size_t)EP * 4);
  int*    deg   = (int*)alloc((size_t)NN * 4);
  int*    cursor= (int*)alloc((size_t)NN * 4);
  int*    rowptr= (int*)alloc((size_t)(NN + 1) * 4);
  int*    bsum  = (int*)alloc(256 * 4);

  hipMemsetAsync(deg, 0, (size_t)NN * 4, stream);
  hipMemsetAsync(cursor, 0, (size_t)NN * 4, stream);

  const int nbScan = (NN + 1023) / 1024;  // 49
  k_hist<<<(EP + 255) / 256, 256, 0, stream>>>(ei, deg);
  k_scan1<<<nbScan, 1024, 0, stream>>>(deg, rowptr + 1, bsum, NN);
  k_scan2<<<1, 64, 0, stream>>>(bsum, nbScan);
  k_scan3<<<(NN + 255) / 256, 256, 0, stream>>>(rowptr, bsum, NN);
  k_scatter<<<(EP + 255) / 256, 256, 0, stream>>>(ei, rowptr, cursor, srcS);

  k_cvt_x<<<2048, 256, 0, stream>>>(x, Xb);
  k_cvt_w1t<<<(HC * (FIN / 8) + 255) / 256, 256, 0, stream>>>(W1, Wt);

  dim3 g1((NN + 127) / 128, HC / 128);  // 391 x 2
  k_gemm1_mfma<<<g1, 256, 0, stream>>>(Xb, Wt, h1b);
  k_alpha1<<<(NN * NH + 255) / 256, 256, 0, stream>>>(h1b, a_src1, a_dst1, asrc1, adst1);
  k_agg1<<<(NN + 3) / 4, 256, 0, stream>>>(h1b, asrc1, adst1, srcS, rowptr, b1, helu);

  k_gemm2<<<(NN + G2_BM - 1) / G2_BM, 256, 0, stream>>>(helu, W2, h2b);
  k_alpha2<<<(NN + 255) / 256, 256, 0, stream>>>(h2b, a_src2, a_dst2, asrc2, adst2);
  k_agg2<<<(NN + 3) / 4, 256, 0, stream>>>(h2b, asrc2, adst2, srcS, rowptr, b2, out);
}

// Round 4
// 364.678 us; speedup vs baseline: 1.6371x; 1.1035x over previous
//
#include <hip/hip_runtime.h>
#include <hip/hip_bf16.h>
#include <math.h>

// Problem constants (from reference)
constexpr int NN  = 50000;          // nodes
constexpr int NE  = 800000;         // edges (before self loops)
constexpr int EP  = NE + NN;        // edges + self loops = 850000
constexpr int FIN = 512;
constexpr int NH  = 8;
constexpr int NC  = 32;
constexpr int HC  = NH * NC;        // 256
constexpr int CLS = 40;
constexpr int CLSP = 48;            // padded classes for MFMA

typedef __attribute__((ext_vector_type(8))) __bf16 bf16x8;
typedef __attribute__((ext_vector_type(4))) __bf16 bf16x4;
typedef __attribute__((ext_vector_type(4))) float f32x4;

__device__ inline bf16x8 cvt8(const float4 a, const float4 b) {
  bf16x8 o;
  o[0] = (__bf16)a.x; o[1] = (__bf16)a.y; o[2] = (__bf16)a.z; o[3] = (__bf16)a.w;
  o[4] = (__bf16)b.x; o[5] = (__bf16)b.y; o[6] = (__bf16)b.z; o[7] = (__bf16)b.w;
  return o;
}

// ---------------------------------------------------------------------------
// CSR build: histogram -> scan -> scatter (sort edges by dst)
// ---------------------------------------------------------------------------
__global__ void k_hist(const int* __restrict__ ei, int* __restrict__ deg) {
  int e = blockIdx.x * 256 + threadIdx.x;
  if (e >= EP) return;
  int d = (e < NE) ? ei[NE + e] : (e - NE);
  atomicAdd(&deg[d], 1);
}

__global__ __launch_bounds__(1024) void k_scan1(const int* __restrict__ deg,
                                                int* __restrict__ rowptr1,
                                                int* __restrict__ bsum, int n) {
  __shared__ int sm[1024];
  int i = blockIdx.x * 1024 + threadIdx.x;
  int v = (i < n) ? deg[i] : 0;
  sm[threadIdx.x] = v;
  __syncthreads();
  for (int off = 1; off < 1024; off <<= 1) {
    int t = (threadIdx.x >= off) ? sm[threadIdx.x - off] : 0;
    __syncthreads();
    sm[threadIdx.x] += t;
    __syncthreads();
  }
  if (i < n) rowptr1[i] = sm[threadIdx.x];
  if (threadIdx.x == 1023) bsum[blockIdx.x] = sm[1023];
}

__global__ void k_scan2(int* __restrict__ bsum, int nb) {
  if (blockIdx.x == 0 && threadIdx.x == 0) {
    int run = 0;
    for (int b = 0; b < nb; ++b) { int t = bsum[b]; bsum[b] = run; run += t; }
  }
}

__global__ void k_scan3(int* __restrict__ rowptr, const int* __restrict__ bsum, int n) {
  int i = blockIdx.x * 256 + threadIdx.x;
  if (i == 0) rowptr[0] = 0;
  if (i < n) rowptr[i + 1] += bsum[i >> 10];
}

__global__ void k_scatter(const int* __restrict__ ei, const int* __restrict__ rowptr,
                          int* __restrict__ cursor, int* __restrict__ srcS) {
  int e = blockIdx.x * 256 + threadIdx.x;
  if (e >= EP) return;
  int s, d;
  if (e < NE) { s = ei[e]; d = ei[NE + e]; } else { s = d = e - NE; }
  int p = rowptr[d] + atomicAdd(&cursor[d], 1);
  srcS[p] = s;
}

// ---------------------------------------------------------------------------
// W1 [512][256] fp32 -> Wt [256][512] bf16 (transposed)
// ---------------------------------------------------------------------------
__global__ void k_cvt_w1t(const float* __restrict__ W1, __bf16* __restrict__ Wt) {
  int t = blockIdx.x * 256 + threadIdx.x;
  if (t >= HC * (FIN / 8)) return;               // 256 * 64
  int c = t >> 6, kq = (t & 63) * 8;
  bf16x8 o;
#pragma unroll
  for (int j = 0; j < 8; ++j) o[j] = (__bf16)W1[(size_t)(kq + j) * HC + c];
  *(bf16x8*)&Wt[(size_t)c * FIN + kq] = o;
}

// W2 [256][40] fp32 -> W2t [48][256] bf16 (transposed, zero-padded cols)
__global__ void k_cvt_w2t(const float* __restrict__ W2, __bf16* __restrict__ W2t) {
  int t = blockIdx.x * 256 + threadIdx.x;
  if (t >= CLSP * HC) return;                    // 48 * 256
  int c = t >> 8, k = t & 255;
  W2t[t] = (c < CLS) ? (__bf16)W2[(size_t)k * CLS + c] : (__bf16)0.f;
}

// ---------------------------------------------------------------------------
// GEMM1 fused (bf16 MFMA): h1b[NN,256](bf16) = bf16(X[NN,512] fp32) @ Wt^T
// BM=64, BN=256 (full width -> X read exactly once), BK=64, 4 waves.
// A: fp32 reg-load -> cvt -> swizzled ds_write_b128.
// B: global_load_lds w=16 from Wt with inverse-swizzled source.
// LDS slot layout (both operands): slot(r,kb) = r*8 + (kb ^ (r&7)), 16B/slot.
// ---------------------------------------------------------------------------
__global__ __launch_bounds__(256) void k_gemm1f(const float* __restrict__ X,
                                                const __bf16* __restrict__ Wt,
                                                __bf16* __restrict__ Hout) {
  __shared__ __align__(16) __bf16 As[64 * 8 * 8];    // 8 KB
  __shared__ __align__(16) __bf16 Bs[256 * 8 * 8];   // 32 KB
  const int tid  = threadIdx.x;
  const int lane = tid & 63;
  const int w    = tid >> 6;              // wave 0..3
  const int wn   = w * 64;
  const int bm   = blockIdx.x * 64;

  // A staging: thread covers row ar (0..63), 16 consecutive k (2 slots)
  const int ar   = tid >> 2;
  const int ak   = (tid & 3) * 16;
  const int kb0  = ak >> 3;               // even slot base
  const int asw  = ar & 7;
  const int arow = min(bm + ar, NN - 1);

  // B staging: inst = w*8+q covers rows inst*8+l3, source slot l7^l3
  const int l3 = lane >> 3;
  const int l7 = lane & 7;
  const int kb_src = l7 ^ l3;

  f32x4 acc[4][4] = {};

  for (int k0 = 0; k0 < FIN; k0 += 64) {
#pragma unroll
    for (int q = 0; q < 8; ++q) {
      const int inst = w * 8 + q;         // 0..31, rows inst*8..inst*8+7
      const int r = inst * 8 + l3;
      const __bf16* gb = Wt + (size_t)r * FIN + k0 + kb_src * 8;
      __builtin_amdgcn_global_load_lds(
          (const __attribute__((address_space(1))) void*)gb,
          (__attribute__((address_space(3))) void*)(Bs + inst * 512), 16, 0, 0);
    }
    {
      const float* gx = &X[(size_t)arow * FIN + k0 + ak];
      float4 f0 = *(const float4*)(gx + 0);
      float4 f1 = *(const float4*)(gx + 4);
      float4 f2 = *(const float4*)(gx + 8);
      float4 f3 = *(const float4*)(gx + 12);
      *(bf16x8*)(As + (size_t)(ar * 8 + (kb0 ^ asw)) * 8)       = cvt8(f0, f1);
      *(bf16x8*)(As + (size_t)(ar * 8 + ((kb0 + 1) ^ asw)) * 8) = cvt8(f2, f3);
    }
    __syncthreads();

    const int l15 = lane & 15, lg = lane >> 4;
#pragma unroll
    for (int kh = 0; kh < 2; ++kh) {
      const int kb = lg + 4 * kh;
      bf16x8 av[4], bv[4];
#pragma unroll
      for (int mi = 0; mi < 4; ++mi) {
        int r = mi * 16 + l15;
        av[mi] = *(const bf16x8*)(As + (size_t)(r * 8 + (kb ^ (r & 7))) * 8);
      }
#pragma unroll
      for (int ni = 0; ni < 4; ++ni) {
        int c = wn + ni * 16 + l15;
        bv[ni] = *(const bf16x8*)(Bs + (size_t)(c * 8 + (kb ^ (c & 7))) * 8);
      }
#pragma unroll
      for (int mi = 0; mi < 4; ++mi)
#pragma unroll
        for (int ni = 0; ni < 4; ++ni)
          acc[mi][ni] = __builtin_amdgcn_mfma_f32_16x16x32_bf16(
              av[mi], bv[ni], acc[mi][ni], 0, 0, 0);
    }
    __syncthreads();
  }

  // epilogue: C/D layout col = lane&15, row = (lane>>4)*4 + reg; store bf16
  const int l15 = lane & 15, lg = lane >> 4;
#pragma unroll
  for (int mi = 0; mi < 4; ++mi) {
#pragma unroll
    for (int ni = 0; ni < 4; ++ni) {
      int col = wn + ni * 16 + l15;
#pragma unroll
      for (int r = 0; r < 4; ++r) {
        int row = bm + mi * 16 + lg * 4 + r;
        if (row < NN) Hout[(size_t)row * HC + col] = (__bf16)acc[mi][ni][r];
      }
    }
  }
}

// ---------------------------------------------------------------------------
// alpha1: per (node, head) dot products with a_src1/a_dst1 (bf16 h1)
// ---------------------------------------------------------------------------
__global__ void k_alpha1(const __bf16* __restrict__ h1b, const float* __restrict__ a_s,
                         const float* __restrict__ a_d, float* __restrict__ asrc,
                         float* __restrict__ adst) {
  int i = blockIdx.x * 256 + threadIdx.x;
  if (i >= NN * NH) return;
  int n = i >> 3, h = i & 7;
  const __bf16* hp = &h1b[(size_t)n * HC + h * NC];
  const float* as = &a_s[h * NC];
  const float* ad = &a_d[h * NC];
  float s = 0.f, d = 0.f;
#pragma unroll
  for (int q = 0; q < 4; ++q) {
    bf16x8 v = *(const bf16x8*)&hp[q * 8];
#pragma unroll
    for (int j = 0; j < 8; ++j) {
      float f = (float)v[j];
      s += f * as[q * 8 + j];
      d += f * ad[q * 8 + j];
    }
  }
  asrc[i] = s;
  adst[i] = d;
}

// ---------------------------------------------------------------------------
// agg1: one wave per dst node; lanes cover 256 channels (bf16x4 = 8B/lane).
// Inline edge weights; output elu(acc/den + b1) as bf16.
// ---------------------------------------------------------------------------
__global__ __launch_bounds__(256) void k_agg1(const __bf16* __restrict__ h1b,
                                              const float* __restrict__ asrc,
                                              const float* __restrict__ adst,
                                              const int* __restrict__ srcS,
                                              const int* __restrict__ rowptr,
                                              const float* __restrict__ b1,
                                              __bf16* __restrict__ helu) {
  int wave = (blockIdx.x * 256 + threadIdx.x) >> 6;
  int lane = threadIdx.x & 63;
  if (wave >= NN) return;
  int lo = rowptr[wave], hi = rowptr[wave + 1];
  int head = lane >> 3;
  float adstv = adst[wave * NH + head];
  float4 acc = {0.f, 0.f, 0.f, 0.f};
  float den = 0.f;
  for (int i = lo; i < hi; ++i) {
    int s = srcS[i];
    float v = asrc[s * NH + head] + adstv;
    v = v > 0.f ? v : 0.2f * v;
    float w = __expf(v);
    bf16x4 hv = *(const bf16x4*)&h1b[(size_t)s * HC + lane * 4];
    acc.x += w * (float)hv[0];
    acc.y += w * (float)hv[1];
    acc.z += w * (float)hv[2];
    acc.w += w * (float)hv[3];
    den += w;
  }
  float inv = 1.f / (den + 1e-16f);
  float4 bb = *(const float4*)&b1[lane * 4];
  float o[4] = {acc.x * inv + bb.x, acc.y * inv + bb.y,
                acc.z * inv + bb.z, acc.w * inv + bb.w};
  bf16x4 ov;
#pragma unroll
  for (int j = 0; j < 4; ++j) {
    float e = o[j] > 0.f ? o[j] : expm1f(o[j]);
    ov[j] = (__bf16)e;
  }
  *(bf16x4*)&helu[(size_t)wave * HC + lane * 4] = ov;
}

// ---------------------------------------------------------------------------
// GEMM2 (bf16 MFMA): h2b[NN,40] = helu[NN,256] @ W2t^T (48 padded cols)
// BM=128, 4 waves (wave = 32 rows x 48 cols), BK=64 A-staging via
// global_load_lds; whole B in padded LDS (stride 33 slots -> spread banks).
// ---------------------------------------------------------------------------
__global__ __launch_bounds__(256) void k_gemm2m(const __bf16* __restrict__ A,
                                                const __bf16* __restrict__ W2t,
                                                __bf16* __restrict__ Hout) {
  __shared__ __align__(16) __bf16 As[128 * 8 * 8];       // 16 KB
  __shared__ __align__(16) __bf16 Bsh[CLSP * 33 * 8];    // 25.3 KB padded
  const int tid  = threadIdx.x;
  const int lane = tid & 63;
  const int w    = tid >> 6;
  const int wm   = w * 32;
  const int bm   = blockIdx.x * 128;

  const int l3 = lane >> 3;
  const int l7 = lane & 7;
  const int kb_src = l7 ^ l3;

  // stage whole W2t once: 48 cols x 32 k-slots
  for (int s = tid; s < CLSP * 32; s += 256) {
    int c = s >> 5, kb = s & 31;
    *(bf16x8*)(Bsh + (size_t)(c * 33 + kb) * 8) =
        *(const bf16x8*)(W2t + (size_t)c * HC + kb * 8);
  }

  f32x4 acc[2][3] = {};

  for (int step = 0; step < 4; ++step) {
    const int k0 = step * 64;
#pragma unroll
    for (int q = 0; q < 4; ++q) {
      const int inst = w * 4 + q;          // 0..15, rows inst*8+l3 (0..127)
      const int r = inst * 8 + l3;
      const int arow = min(bm + r, NN - 1);
      const __bf16* ga = A + (size_t)arow * HC + k0 + kb_src * 8;
      __builtin_amdgcn_global_load_lds(
          (const __attribute__((address_space(1))) void*)ga,
          (__attribute__((address_space(3))) void*)(As + inst * 512), 16, 0, 0);
    }
    __syncthreads();

    const int l15 = lane & 15, lg = lane >> 4;
#pragma unroll
    for (int kh = 0; kh < 2; ++kh) {
      const int kbl = lg + 4 * kh;         // local k slot 0..7
      const int kbg = step * 8 + kbl;      // global k slot 0..31
      bf16x8 av[2], bv[3];
#pragma unroll
      for (int mi = 0; mi < 2; ++mi) {
        int r = wm + mi * 16 + l15;
        av[mi] = *(const bf16x8*)(As + (size_t)(r * 8 + (kbl ^ (r & 7))) * 8);
      }
#pragma unroll
      for (int ni = 0; ni < 3; ++ni) {
        int c = ni * 16 + l15;
        bv[ni] = *(const bf16x8*)(Bsh + (size_t)(c * 33 + kbg) * 8);
      }
#pragma unroll
      for (int mi = 0; mi < 2; ++mi)
#pragma unroll
        for (int ni = 0; ni < 3; ++ni)
          acc[mi][ni] = __builtin_amdgcn_mfma_f32_16x16x32_bf16(
              av[mi], bv[ni], acc[mi][ni], 0, 0, 0);
    }
    __syncthreads();
  }

  const int l15 = lane & 15, lg = lane >> 4;
#pragma unroll
  for (int mi = 0; mi < 2; ++mi) {
#pragma unroll
    for (int ni = 0; ni < 3; ++ni) {
      int col = ni * 16 + l15;
      if (col >= CLS) continue;
#pragma unroll
      for (int r = 0; r < 4; ++r) {
        int row = bm + wm + mi * 16 + lg * 4 + r;
        if (row < NN) Hout[(size_t)row * CLS + col] = (__bf16)acc[mi][ni][r];
      }
    }
  }
}

// ---------------------------------------------------------------------------
// alpha2: per-node dots with a_src2/a_dst2 (single head, bf16 h2)
// ---------------------------------------------------------------------------
__global__ void k_alpha2(const __bf16* __restrict__ h2b, const float* __restrict__ a_s,
                         const float* __restrict__ a_d, float* __restrict__ asrc,
                         float* __restrict__ adst) {
  int n = blockIdx.x * 256 + threadIdx.x;
  if (n >= NN) return;
  float s = 0.f, d = 0.f;
#pragma unroll
  for (int q = 0; q < 5; ++q) {
    bf16x8 v = *(const bf16x8*)&h2b[(size_t)n * CLS + q * 8];
#pragma unroll
    for (int j = 0; j < 8; ++j) {
      float f = (float)v[j];
      s += f * a_s[q * 8 + j];
      d += f * a_d[q * 8 + j];
    }
  }
  asrc[n] = s;
  adst[n] = d;
}

// ---------------------------------------------------------------------------
// agg2: one wave per dst node; lanes 0..39 = classes; inline edge weights;
// fused bias + log_softmax.
// ---------------------------------------------------------------------------
__global__ __launch_bounds__(256) void k_agg2(const __bf16* __restrict__ h2b,
                                              const float* __restrict__ asrc,
                                              const float* __restrict__ adst,
                                              const int* __restrict__ srcS,
                                              const int* __restrict__ rowptr,
                                              const float* __restrict__ b2,
                                              float* __restrict__ out) {
  int wave = (blockIdx.x * 256 + threadIdx.x) >> 6;
  int lane = threadIdx.x & 63;
  if (wave >= NN) return;
  int lo = rowptr[wave], hi = rowptr[wave + 1];
  bool act = lane < CLS;
  float adstv = adst[wave];
  float acc = 0.f, den = 0.f;
  for (int i = lo; i < hi; ++i) {
    int s = srcS[i];
    float v = asrc[s] + adstv;
    v = v > 0.f ? v : 0.2f * v;
    float w = __expf(v);
    den += w;
    if (act) acc += w * (float)h2b[(size_t)s * CLS + lane];
  }
  float o = act ? (acc / (den + 1e-16f) + b2[lane]) : -INFINITY;
  float m = o;
#pragma unroll
  for (int off = 32; off; off >>= 1) m = fmaxf(m, __shfl_xor(m, off, 64));
  float ex = act ? __expf(o - m) : 0.f;
  float ssum = ex;
#pragma unroll
  for (int off = 32; off; off >>= 1) ssum += __shfl_xor(ssum, off, 64);
  if (act) out[(size_t)wave * CLS + lane] = o - m - logf(ssum);
}

// ---------------------------------------------------------------------------
extern "C" void kernel_launch(void* const* d_in, const int* in_sizes, int n_in,
                              void* d_out, int out_size, void* d_ws, size_t ws_size,
                              hipStream_t stream) {
  const float* x      = (const float*)d_in[0];
  const int*   ei     = (const int*)d_in[1];
  const float* W1     = (const float*)d_in[2];
  const float* a_src1 = (const float*)d_in[3];
  const float* a_dst1 = (const float*)d_in[4];
  const float* b1     = (const float*)d_in[5];
  const float* W2     = (const float*)d_in[6];
  const float* a_src2 = (const float*)d_in[7];
  const float* a_dst2 = (const float*)d_in[8];
  const float* b2     = (const float*)d_in[9];
  float* out = (float*)d_out;

  char* p = (char*)d_ws;
  auto alloc = [&](size_t bytes) {
    char* r = p;
    p += (bytes + 255) & ~size_t(255);
    return r;
  };
  __bf16* h1b   = (__bf16*)alloc((size_t)NN * HC * 2);    // 25.6 MB
  __bf16* helu  = (__bf16*)alloc((size_t)NN * HC * 2);    // 25.6 MB
  __bf16* Wt    = (__bf16*)alloc((size_t)HC * FIN * 2);   // 256 KB
  __bf16* W2t   = (__bf16*)alloc((size_t)CLSP * HC * 2);  // 24 KB
  __bf16* h2b   = (__bf16*)alloc((size_t)NN * CLS * 2);   // 4 MB
  float*  asrc1 = (float*)alloc((size_t)NN * NH * 4);
  float*  adst1 = (float*)alloc((size_t)NN * NH * 4);
  float*  asrc2 = (float*)alloc((size_t)NN * 4);
  float*  adst2 = (float*)alloc((size_t)NN * 4);
  int*    srcS  = (int*)alloc((size_t)EP * 4);
  int*    deg   = (int*)alloc((size_t)NN * 4);
  int*    cursor= (int*)alloc((size_t)NN * 4);
  int*    rowptr= (int*)alloc((size_t)(NN + 1) * 4);
  int*    bsum  = (int*)alloc(256 * 4);

  hipMemsetAsync(deg, 0, (size_t)NN * 4, stream);
  hipMemsetAsync(cursor, 0, (size_t)NN * 4, stream);

  const int nbScan = (NN + 1023) / 1024;  // 49
  k_hist<<<(EP + 255) / 256, 256, 0, stream>>>(ei, deg);
  k_scan1<<<nbScan, 1024, 0, stream>>>(deg, rowptr + 1, bsum, NN);
  k_scan2<<<1, 64, 0, stream>>>(bsum, nbScan);
  k_scan3<<<(NN + 255) / 256, 256, 0, stream>>>(rowptr, bsum, NN);
  k_scatter<<<(EP + 255) / 256, 256, 0, stream>>>(ei, rowptr, cursor, srcS);

  k_cvt_w1t<<<(HC * (FIN / 8) + 255) / 256, 256, 0, stream>>>(W1, Wt);
  k_cvt_w2t<<<(CLSP * HC + 255) / 256, 256, 0, stream>>>(W2, W2t);

  k_gemm1f<<<(NN + 63) / 64, 256, 0, stream>>>(x, Wt, h1b);
  k_alpha1<<<(NN * NH + 255) / 256, 256, 0, stream>>>(h1b, a_src1, a_dst1, asrc1, adst1);
  k_agg1<<<(NN + 3) / 4, 256, 0, stream>>>(h1b, asrc1, adst1, srcS, rowptr, b1, helu);

  k_gemm2m<<<(NN + 127) / 128, 256, 0, stream>>>(helu, W2t, h2b);
  k_alpha2<<<(NN + 255) / 256, 256, 0, stream>>>(h2b, a_src2, a_dst2, asrc2, adst2);
  k_agg2<<<(NN + 3) / 4, 256, 0, stream>>>(h2b, asrc2, adst2, srcS, rowptr, b2, out);
}

// Round 5
// 288.447 us; speedup vs baseline: 2.0697x; 1.2643x over previous
//
#include <hip/hip_runtime.h>
#include <hip/hip_bf16.h>
#include <math.h>

// Problem constants (from reference)
constexpr int NN  = 50000;          // nodes
constexpr int NE  = 800000;         // edges (before self loops)
constexpr int EP  = NE + NN;        // edges + self loops = 850000
constexpr int FIN = 512;
constexpr int NH  = 8;
constexpr int NC  = 32;
constexpr int HC  = NH * NC;        // 256
constexpr int CLS = 40;
constexpr int CLSP = 48;            // padded classes for MFMA

typedef __attribute__((ext_vector_type(8))) __bf16 bf16x8;
typedef __attribute__((ext_vector_type(4))) __bf16 bf16x4;
typedef __attribute__((ext_vector_type(4))) float f32x4;

__device__ inline bf16x8 cvt8(const float4 a, const float4 b) {
  bf16x8 o;
  o[0] = (__bf16)a.x; o[1] = (__bf16)a.y; o[2] = (__bf16)a.z; o[3] = (__bf16)a.w;
  o[4] = (__bf16)b.x; o[5] = (__bf16)b.y; o[6] = (__bf16)b.z; o[7] = (__bf16)b.w;
  return o;
}

// ---------------------------------------------------------------------------
// CSR build: histogram -> scan -> scatter (sort edges by dst)
// ---------------------------------------------------------------------------
__global__ void k_hist(const int* __restrict__ ei, int* __restrict__ deg) {
  int e = blockIdx.x * 256 + threadIdx.x;
  if (e >= EP) return;
  int d = (e < NE) ? ei[NE + e] : (e - NE);
  atomicAdd(&deg[d], 1);
}

__global__ __launch_bounds__(1024) void k_scan1(const int* __restrict__ deg,
                                                int* __restrict__ rowptr1,
                                                int* __restrict__ bsum, int n) {
  __shared__ int sm[1024];
  int i = blockIdx.x * 1024 + threadIdx.x;
  int v = (i < n) ? deg[i] : 0;
  sm[threadIdx.x] = v;
  __syncthreads();
  for (int off = 1; off < 1024; off <<= 1) {
    int t = (threadIdx.x >= off) ? sm[threadIdx.x - off] : 0;
    __syncthreads();
    sm[threadIdx.x] += t;
    __syncthreads();
  }
  if (i < n) rowptr1[i] = sm[threadIdx.x];
  if (threadIdx.x == 1023) bsum[blockIdx.x] = sm[1023];
}

__global__ void k_scan2(int* __restrict__ bsum, int nb) {
  if (blockIdx.x == 0 && threadIdx.x == 0) {
    int run = 0;
    for (int b = 0; b < nb; ++b) { int t = bsum[b]; bsum[b] = run; run += t; }
  }
}

__global__ void k_scan3(int* __restrict__ rowptr, const int* __restrict__ bsum, int n) {
  int i = blockIdx.x * 256 + threadIdx.x;
  if (i == 0) rowptr[0] = 0;
  if (i < n) rowptr[i + 1] += bsum[i >> 10];
}

__global__ void k_scatter(const int* __restrict__ ei, const int* __restrict__ rowptr,
                          int* __restrict__ cursor, int* __restrict__ srcS) {
  int e = blockIdx.x * 256 + threadIdx.x;
  if (e >= EP) return;
  int s, d;
  if (e < NE) { s = ei[e]; d = ei[NE + e]; } else { s = d = e - NE; }
  int p = rowptr[d] + atomicAdd(&cursor[d], 1);
  srcS[p] = s;
}

// ---------------------------------------------------------------------------
// W1 [512][256] fp32 -> Wt [256][512] bf16 (transposed)
// ---------------------------------------------------------------------------
__global__ void k_cvt_w1t(const float* __restrict__ W1, __bf16* __restrict__ Wt) {
  int t = blockIdx.x * 256 + threadIdx.x;
  if (t >= HC * (FIN / 8)) return;               // 256 * 64
  int c = t >> 6, kq = (t & 63) * 8;
  bf16x8 o;
#pragma unroll
  for (int j = 0; j < 8; ++j) o[j] = (__bf16)W1[(size_t)(kq + j) * HC + c];
  *(bf16x8*)&Wt[(size_t)c * FIN + kq] = o;
}

// W2 [256][40] fp32 -> W2t [48][256] bf16 (transposed, zero-padded cols)
__global__ void k_cvt_w2t(const float* __restrict__ W2, __bf16* __restrict__ W2t) {
  int t = blockIdx.x * 256 + threadIdx.x;
  if (t >= CLSP * HC) return;                    // 48 * 256
  int c = t >> 8, k = t & 255;
  W2t[t] = (c < CLS) ? (__bf16)W2[(size_t)k * CLS + c] : (__bf16)0.f;
}

// ---------------------------------------------------------------------------
// GEMM1 fused (bf16 MFMA): h1b[NN,256](bf16) = bf16(X[NN,512] fp32) @ Wt^T
// BM=64, BN=256 (full width -> X read exactly once), BK=64, 4 waves.
// ---------------------------------------------------------------------------
__global__ __launch_bounds__(256) void k_gemm1f(const float* __restrict__ X,
                                                const __bf16* __restrict__ Wt,
                                                __bf16* __restrict__ Hout) {
  __shared__ __align__(16) __bf16 As[64 * 8 * 8];    // 8 KB
  __shared__ __align__(16) __bf16 Bs[256 * 8 * 8];   // 32 KB
  const int tid  = threadIdx.x;
  const int lane = tid & 63;
  const int w    = tid >> 6;              // wave 0..3
  const int wn   = w * 64;
  const int bm   = blockIdx.x * 64;

  const int ar   = tid >> 2;
  const int ak   = (tid & 3) * 16;
  const int kb0  = ak >> 3;
  const int asw  = ar & 7;
  const int arow = min(bm + ar, NN - 1);

  const int l3 = lane >> 3;
  const int l7 = lane & 7;
  const int kb_src = l7 ^ l3;

  f32x4 acc[4][4] = {};

  for (int k0 = 0; k0 < FIN; k0 += 64) {
#pragma unroll
    for (int q = 0; q < 8; ++q) {
      const int inst = w * 8 + q;
      const int r = inst * 8 + l3;
      const __bf16* gb = Wt + (size_t)r * FIN + k0 + kb_src * 8;
      __builtin_amdgcn_global_load_lds(
          (const __attribute__((address_space(1))) void*)gb,
          (__attribute__((address_space(3))) void*)(Bs + inst * 512), 16, 0, 0);
    }
    {
      const float* gx = &X[(size_t)arow * FIN + k0 + ak];
      float4 f0 = *(const float4*)(gx + 0);
      float4 f1 = *(const float4*)(gx + 4);
      float4 f2 = *(const float4*)(gx + 8);
      float4 f3 = *(const float4*)(gx + 12);
      *(bf16x8*)(As + (size_t)(ar * 8 + (kb0 ^ asw)) * 8)       = cvt8(f0, f1);
      *(bf16x8*)(As + (size_t)(ar * 8 + ((kb0 + 1) ^ asw)) * 8) = cvt8(f2, f3);
    }
    __syncthreads();

    const int l15 = lane & 15, lg = lane >> 4;
#pragma unroll
    for (int kh = 0; kh < 2; ++kh) {
      const int kb = lg + 4 * kh;
      bf16x8 av[4], bv[4];
#pragma unroll
      for (int mi = 0; mi < 4; ++mi) {
        int r = mi * 16 + l15;
        av[mi] = *(const bf16x8*)(As + (size_t)(r * 8 + (kb ^ (r & 7))) * 8);
      }
#pragma unroll
      for (int ni = 0; ni < 4; ++ni) {
        int c = wn + ni * 16 + l15;
        bv[ni] = *(const bf16x8*)(Bs + (size_t)(c * 8 + (kb ^ (c & 7))) * 8);
      }
#pragma unroll
      for (int mi = 0; mi < 4; ++mi)
#pragma unroll
        for (int ni = 0; ni < 4; ++ni)
          acc[mi][ni] = __builtin_amdgcn_mfma_f32_16x16x32_bf16(
              av[mi], bv[ni], acc[mi][ni], 0, 0, 0);
    }
    __syncthreads();
  }

  const int l15 = lane & 15, lg = lane >> 4;
#pragma unroll
  for (int mi = 0; mi < 4; ++mi) {
#pragma unroll
    for (int ni = 0; ni < 4; ++ni) {
      int col = wn + ni * 16 + l15;
#pragma unroll
      for (int r = 0; r < 4; ++r) {
        int row = bm + mi * 16 + lg * 4 + r;
        if (row < NN) Hout[(size_t)row * HC + col] = (__bf16)acc[mi][ni][r];
      }
    }
  }
}

// ---------------------------------------------------------------------------
// alpha1: per (node, head) dot products with a_src1/a_dst1 (bf16 h1)
// ---------------------------------------------------------------------------
__global__ void k_alpha1(const __bf16* __restrict__ h1b, const float* __restrict__ a_s,
                         const float* __restrict__ a_d, float* __restrict__ asrc,
                         float* __restrict__ adst) {
  int i = blockIdx.x * 256 + threadIdx.x;
  if (i >= NN * NH) return;
  int n = i >> 3, h = i & 7;
  const __bf16* hp = &h1b[(size_t)n * HC + h * NC];
  const float* as = &a_s[h * NC];
  const float* ad = &a_d[h * NC];
  float s = 0.f, d = 0.f;
#pragma unroll
  for (int q = 0; q < 4; ++q) {
    bf16x8 v = *(const bf16x8*)&hp[q * 8];
#pragma unroll
    for (int j = 0; j < 8; ++j) {
      float f = (float)v[j];
      s += f * as[q * 8 + j];
      d += f * ad[q * 8 + j];
    }
  }
  asrc[i] = s;
  adst[i] = d;
}

// ---------------------------------------------------------------------------
// agg1: one wave per dst node; lanes cover 256 channels (bf16x4 = 8B/lane).
// Chunked srcS broadcast (1 coalesced load / 64 edges) + 4x unrolled body
// for 4-deep memory-level parallelism. Inline edge weights; bf16 output.
// ---------------------------------------------------------------------------
__global__ __launch_bounds__(256) void k_agg1(const __bf16* __restrict__ h1b,
                                              const float* __restrict__ asrc,
                                              const float* __restrict__ adst,
                                              const int* __restrict__ srcS,
                                              const int* __restrict__ rowptr,
                                              const float* __restrict__ b1,
                                              __bf16* __restrict__ helu) {
  int wave = (blockIdx.x * 256 + threadIdx.x) >> 6;
  int lane = threadIdx.x & 63;
  if (wave >= NN) return;
  int lo = rowptr[wave], hi = rowptr[wave + 1];
  int head = lane >> 3;
  float adstv = adst[wave * NH + head];
  float4 acc = {0.f, 0.f, 0.f, 0.f};
  float den = 0.f;

  for (int base = lo; base < hi; base += 64) {
    int cnt = hi - base; if (cnt > 64) cnt = 64;
    int sv = (lane < cnt) ? srcS[base + lane] : 0;
    int j = 0;
    for (; j + 4 <= cnt; j += 4) {
      int s[4]; float e[4]; bf16x4 hv[4];
#pragma unroll
      for (int u = 0; u < 4; ++u) s[u] = __shfl(sv, j + u);
#pragma unroll
      for (int u = 0; u < 4; ++u) e[u] = asrc[s[u] * NH + head];
#pragma unroll
      for (int u = 0; u < 4; ++u)
        hv[u] = *(const bf16x4*)&h1b[(size_t)s[u] * HC + lane * 4];
#pragma unroll
      for (int u = 0; u < 4; ++u) {
        float v = e[u] + adstv;
        v = v > 0.f ? v : 0.2f * v;
        float w = __expf(v);
        acc.x += w * (float)hv[u][0];
        acc.y += w * (float)hv[u][1];
        acc.z += w * (float)hv[u][2];
        acc.w += w * (float)hv[u][3];
        den += w;
      }
    }
    for (; j < cnt; ++j) {
      int s = __shfl(sv, j);
      float v = asrc[s * NH + head] + adstv;
      v = v > 0.f ? v : 0.2f * v;
      float w = __expf(v);
      bf16x4 hv = *(const bf16x4*)&h1b[(size_t)s * HC + lane * 4];
      acc.x += w * (float)hv[0];
      acc.y += w * (float)hv[1];
      acc.z += w * (float)hv[2];
      acc.w += w * (float)hv[3];
      den += w;
    }
  }

  float inv = 1.f / (den + 1e-16f);
  float4 bb = *(const float4*)&b1[lane * 4];
  float o[4] = {acc.x * inv + bb.x, acc.y * inv + bb.y,
                acc.z * inv + bb.z, acc.w * inv + bb.w};
  bf16x4 ov;
#pragma unroll
  for (int j2 = 0; j2 < 4; ++j2) {
    float e = o[j2] > 0.f ? o[j2] : expm1f(o[j2]);
    ov[j2] = (__bf16)e;
  }
  *(bf16x4*)&helu[(size_t)wave * HC + lane * 4] = ov;
}

// ---------------------------------------------------------------------------
// GEMM2 (bf16 MFMA): h2b[NN,40] = helu[NN,256] @ W2t^T (48 padded cols)
// ---------------------------------------------------------------------------
__global__ __launch_bounds__(256) void k_gemm2m(const __bf16* __restrict__ A,
                                                const __bf16* __restrict__ W2t,
                                                __bf16* __restrict__ Hout) {
  __shared__ __align__(16) __bf16 As[128 * 8 * 8];       // 16 KB
  __shared__ __align__(16) __bf16 Bsh[CLSP * 33 * 8];    // 25.3 KB padded
  const int tid  = threadIdx.x;
  const int lane = tid & 63;
  const int w    = tid >> 6;
  const int wm   = w * 32;
  const int bm   = blockIdx.x * 128;

  const int l3 = lane >> 3;
  const int l7 = lane & 7;
  const int kb_src = l7 ^ l3;

  for (int s = tid; s < CLSP * 32; s += 256) {
    int c = s >> 5, kb = s & 31;
    *(bf16x8*)(Bsh + (size_t)(c * 33 + kb) * 8) =
        *(const bf16x8*)(W2t + (size_t)c * HC + kb * 8);
  }

  f32x4 acc[2][3] = {};

  for (int step = 0; step < 4; ++step) {
    const int k0 = step * 64;
#pragma unroll
    for (int q = 0; q < 4; ++q) {
      const int inst = w * 4 + q;
      const int r = inst * 8 + l3;
      const int arow = min(bm + r, NN - 1);
      const __bf16* ga = A + (size_t)arow * HC + k0 + kb_src * 8;
      __builtin_amdgcn_global_load_lds(
          (const __attribute__((address_space(1))) void*)ga,
          (__attribute__((address_space(3))) void*)(As + inst * 512), 16, 0, 0);
    }
    __syncthreads();

    const int l15 = lane & 15, lg = lane >> 4;
#pragma unroll
    for (int kh = 0; kh < 2; ++kh) {
      const int kbl = lg + 4 * kh;
      const int kbg = step * 8 + kbl;
      bf16x8 av[2], bv[3];
#pragma unroll
      for (int mi = 0; mi < 2; ++mi) {
        int r = wm + mi * 16 + l15;
        av[mi] = *(const bf16x8*)(As + (size_t)(r * 8 + (kbl ^ (r & 7))) * 8);
      }
#pragma unroll
      for (int ni = 0; ni < 3; ++ni) {
        int c = ni * 16 + l15;
        bv[ni] = *(const bf16x8*)(Bsh + (size_t)(c * 33 + kbg) * 8);
      }
#pragma unroll
      for (int mi = 0; mi < 2; ++mi)
#pragma unroll
        for (int ni = 0; ni < 3; ++ni)
          acc[mi][ni] = __builtin_amdgcn_mfma_f32_16x16x32_bf16(
              av[mi], bv[ni], acc[mi][ni], 0, 0, 0);
    }
    __syncthreads();
  }

  const int l15 = lane & 15, lg = lane >> 4;
#pragma unroll
  for (int mi = 0; mi < 2; ++mi) {
#pragma unroll
    for (int ni = 0; ni < 3; ++ni) {
      int col = ni * 16 + l15;
      if (col >= CLS) continue;
#pragma unroll
      for (int r = 0; r < 4; ++r) {
        int row = bm + wm + mi * 16 + lg * 4 + r;
        if (row < NN) Hout[(size_t)row * CLS + col] = (__bf16)acc[mi][ni][r];
      }
    }
  }
}

// ---------------------------------------------------------------------------
// alpha2: per-node dots with a_src2/a_dst2 (single head, bf16 h2)
// ---------------------------------------------------------------------------
__global__ void k_alpha2(const __bf16* __restrict__ h2b, const float* __restrict__ a_s,
                         const float* __restrict__ a_d, float* __restrict__ asrc,
                         float* __restrict__ adst) {
  int n = blockIdx.x * 256 + threadIdx.x;
  if (n >= NN) return;
  float s = 0.f, d = 0.f;
#pragma unroll
  for (int q = 0; q < 5; ++q) {
    bf16x8 v = *(const bf16x8*)&h2b[(size_t)n * CLS + q * 8];
#pragma unroll
    for (int j = 0; j < 8; ++j) {
      float f = (float)v[j];
      s += f * a_s[q * 8 + j];
      d += f * a_d[q * 8 + j];
    }
  }
  asrc[n] = s;
  adst[n] = d;
}

// ---------------------------------------------------------------------------
// agg2: one wave per dst node; lanes 0..39 = classes; chunked srcS broadcast
// + 4x unroll; inline edge weights; fused bias + log_softmax.
// ---------------------------------------------------------------------------
__global__ __launch_bounds__(256) void k_agg2(const __bf16* __restrict__ h2b,
                                              const float* __restrict__ asrc,
                                              const float* __restrict__ adst,
                                              const int* __restrict__ srcS,
                                              const int* __restrict__ rowptr,
                                              const float* __restrict__ b2,
                                              float* __restrict__ out) {
  int wave = (blockIdx.x * 256 + threadIdx.x) >> 6;
  int lane = threadIdx.x & 63;
  if (wave >= NN) return;
  int lo = rowptr[wave], hi = rowptr[wave + 1];
  bool act = lane < CLS;
  float adstv = adst[wave];
  float acc = 0.f, den = 0.f;

  for (int base = lo; base < hi; base += 64) {
    int cnt = hi - base; if (cnt > 64) cnt = 64;
    int sv = (lane < cnt) ? srcS[base + lane] : 0;
    int j = 0;
    for (; j + 4 <= cnt; j += 4) {
      int s[4]; float e[4]; float hval[4];
#pragma unroll
      for (int u = 0; u < 4; ++u) s[u] = __shfl(sv, j + u);
#pragma unroll
      for (int u = 0; u < 4; ++u) e[u] = asrc[s[u]];
#pragma unroll
      for (int u = 0; u < 4; ++u)
        hval[u] = act ? (float)h2b[(size_t)s[u] * CLS + lane] : 0.f;
#pragma unroll
      for (int u = 0; u < 4; ++u) {
        float v = e[u] + adstv;
        v = v > 0.f ? v : 0.2f * v;
        float w = __expf(v);
        acc += w * hval[u];
        den += w;
      }
    }
    for (; j < cnt; ++j) {
      int s = __shfl(sv, j);
      float v = asrc[s] + adstv;
      v = v > 0.f ? v : 0.2f * v;
      float w = __expf(v);
      if (act) acc += w * (float)h2b[(size_t)s * CLS + lane];
      den += w;
    }
  }

  float o = act ? (acc / (den + 1e-16f) + b2[lane]) : -INFINITY;
  float m = o;
#pragma unroll
  for (int off = 32; off; off >>= 1) m = fmaxf(m, __shfl_xor(m, off, 64));
  float ex = act ? __expf(o - m) : 0.f;
  float ssum = ex;
#pragma unroll
  for (int off = 32; off; off >>= 1) ssum += __shfl_xor(ssum, off, 64);
  if (act) out[(size_t)wave * CLS + lane] = o - m - logf(ssum);
}

// ---------------------------------------------------------------------------
extern "C" void kernel_launch(void* const* d_in, const int* in_sizes, int n_in,
                              void* d_out, int out_size, void* d_ws, size_t ws_size,
                              hipStream_t stream) {
  const float* x      = (const float*)d_in[0];
  const int*   ei     = (const int*)d_in[1];
  const float* W1     = (const float*)d_in[2];
  const float* a_src1 = (const float*)d_in[3];
  const float* a_dst1 = (const float*)d_in[4];
  const float* b1     = (const float*)d_in[5];
  const float* W2     = (const float*)d_in[6];
  const float* a_src2 = (const float*)d_in[7];
  const float* a_dst2 = (const float*)d_in[8];
  const float* b2     = (const float*)d_in[9];
  float* out = (float*)d_out;

  char* p = (char*)d_ws;
  auto alloc = [&](size_t bytes) {
    char* r = p;
    p += (bytes + 255) & ~size_t(255);
    return r;
  };
  __bf16* h1b   = (__bf16*)alloc((size_t)NN * HC * 2);    // 25.6 MB
  __bf16* helu  = (__bf16*)alloc((size_t)NN * HC * 2);    // 25.6 MB
  __bf16* Wt    = (__bf16*)alloc((size_t)HC * FIN * 2);   // 256 KB
  __bf16* W2t   = (__bf16*)alloc((size_t)CLSP * HC * 2);  // 24 KB
  __bf16* h2b   = (__bf16*)alloc((size_t)NN * CLS * 2);   // 4 MB
  float*  asrc1 = (float*)alloc((size_t)NN * NH * 4);
  float*  adst1 = (float*)alloc((size_t)NN * NH * 4);
  float*  asrc2 = (float*)alloc((size_t)NN * 4);
  float*  adst2 = (float*)alloc((size_t)NN * 4);
  int*    srcS  = (int*)alloc((size_t)EP * 4);
  int*    deg   = (int*)alloc((size_t)NN * 4);
  int*    cursor= (int*)alloc((size_t)NN * 4);
  int*    rowptr= (int*)alloc((size_t)(NN + 1) * 4);
  int*    bsum  = (int*)alloc(256 * 4);

  hipMemsetAsync(deg, 0, (size_t)NN * 4, stream);
  hipMemsetAsync(cursor, 0, (size_t)NN * 4, stream);

  const int nbScan = (NN + 1023) / 1024;  // 49
  k_hist<<<(EP + 255) / 256, 256, 0, stream>>>(ei, deg);
  k_scan1<<<nbScan, 1024, 0, stream>>>(deg, rowptr + 1, bsum, NN);
  k_scan2<<<1, 64, 0, stream>>>(bsum, nbScan);
  k_scan3<<<(NN + 255) / 256, 256, 0, stream>>>(rowptr, bsum, NN);
  k_scatter<<<(EP + 255) / 256, 256, 0, stream>>>(ei, rowptr, cursor, srcS);

  k_cvt_w1t<<<(HC * (FIN / 8) + 255) / 256, 256, 0, stream>>>(W1, Wt);
  k_cvt_w2t<<<(CLSP * HC + 255) / 256, 256, 0, stream>>>(W2, W2t);

  k_gemm1f<<<(NN + 63) / 64, 256, 0, stream>>>(x, Wt, h1b);
  k_alpha1<<<(NN * NH + 255) / 256, 256, 0, stream>>>(h1b, a_src1, a_dst1, asrc1, adst1);
  k_agg1<<<(NN + 3) / 4, 256, 0, stream>>>(h1b, asrc1, adst1, srcS, rowptr, b1, helu);

  k_gemm2m<<<(NN + 127) / 128, 256, 0, stream>>>(helu, W2t, h2b);
  k_alpha2<<<(NN + 255) / 256, 256, 0, stream>>>(h2b, a_src2, a_dst2, asrc2, adst2);
  k_agg2<<<(NN + 3) / 4, 256, 0, stream>>>(h2b, asrc2, adst2, srcS, rowptr, b2, out);
}